// Round 2
// baseline (2637.536 us; speedup 1.0000x reference)
//
#include <hip/hip_runtime.h>
#include <hip/hip_bf16.h>

// ---------------- static problem config ----------------
#define BDIM 16
#define CDIM 32
#define LDIM 512
#define TDIM 65            // all_topk
#define DDIM 512
#define BC   (BDIM*CDIM)   // 512
#define MROWS (BC*TDIM)    // 33280
#define LN_EPS 1e-5f

typedef float fx4 __attribute__((ext_vector_type(4)));
typedef __bf16 bf16x8 __attribute__((ext_vector_type(8)));
typedef unsigned short us16;

// ---------------- helpers ----------------
__device__ __forceinline__ us16 f2bf(float f){
  unsigned int u = __float_as_uint(f);
  u = (u + 0x7fffu + ((u >> 16) & 1u)) >> 16;
  return (us16)u;
}
__device__ __forceinline__ float bf2f(us16 s){
  return __uint_as_float(((unsigned int)s) << 16);
}
__device__ __forceinline__ float wred_max(float v){
  #pragma unroll
  for (int o = 32; o; o >>= 1) v = fmaxf(v, __shfl_xor(v, o));
  return v;
}
__device__ __forceinline__ float wred_sum(float v){
  #pragma unroll
  for (int o = 32; o; o >>= 1) v += __shfl_xor(v, o);
  return v;
}
__device__ __forceinline__ float gelu_exact(float x){
  return 0.5f * x * (1.0f + erff(x * 0.70710678118654752440f));
}
__device__ __forceinline__ void async16(void* lds, const void* g){
  __builtin_amdgcn_global_load_lds(
      (const __attribute__((address_space(1))) unsigned int*)g,
      (__attribute__((address_space(3))) unsigned int*)lds, 16, 0, 0);
}

// ---------------- K1: magnitude / phase ----------------
__global__ __launch_bounds__(256) void magph_kernel(
    const float* __restrict__ xr, const float* __restrict__ xi,
    float* __restrict__ mag, float* __restrict__ ph)
{
  int i = blockIdx.x * 256 + threadIdx.x;   // n = 262144 exact
  float r = xr[i], im = xi[i];
  mag[i] = sqrtf(r*r + im*im);
  ph[i]  = atan2f(im, r);
}

// ---------------- K2: per-frequency energy (double accum) ----------------
__global__ __launch_bounds__(64) void gm_kernel(
    const float* __restrict__ mag, double* __restrict__ gm)
{
  int l = blockIdx.x, t = threadIdx.x;
  double acc = 0.0;
  #pragma unroll
  for (int r = 0; r < 8; ++r){
    float v = mag[(size_t)(t + 64*r)*LDIM + l];
    acc += (double)v * (double)v;
  }
  #pragma unroll
  for (int o = 32; o; o >>= 1) acc += __shfl_xor(acc, o);
  if (t == 0) gm[l] = acc;
}

// ---------------- K3: top-k index selection ----------------
__device__ int wave_argmax(const float* val, int lo, int hi, int t){
  float bv = -3.4e38f; int bi = 0x7fffffff;
  for (int i = lo + t; i < hi; i += 64){
    float v = val[i];
    if (v > bv || (v == bv && i < bi)){ bv = v; bi = i; }
  }
  #pragma unroll
  for (int o = 32; o; o >>= 1){
    float ov = __shfl_xor(bv, o); int oi = __shfl_xor(bi, o);
    if (ov > bv || (ov == bv && oi < bi)){ bv = ov; bi = oi; }
  }
  return bi;
}

__global__ __launch_bounds__(64) void topk_kernel(
    const double* __restrict__ gm, int* __restrict__ idxo)
{
  __shared__ float val[LDIM];
  __shared__ float orig[LDIM];
  int t = threadIdx.x;
  for (int i = t; i < LDIM; i += 64){ float v = (float)gm[i]; val[i] = v; orig[i] = v; }
  __syncthreads();
  // global top-32 (argsort(-gm), stable ties -> smaller index)
  for (int s = 0; s < 32; ++s){
    int b = wave_argmax(val, 0, LDIM, t);
    if (t == 0){ idxo[s] = b; val[b] = -3.4e38f; }
    __syncthreads();
  }
  for (int i = t; i < LDIM; i += 64) val[i] = orig[i];
  __syncthreads();
  // 3 bands x top-11
  for (int bb = 0; bb < 3; ++bb){
    int s0 = bb*170, e0 = (bb == 2) ? LDIM : (bb+1)*170;
    for (int s = 0; s < 11; ++s){
      int b = wave_argmax(val, s0, e0, t);
      if (t == 0){ idxo[32 + bb*11 + s] = b; val[b] = -3.4e38f; }
      __syncthreads();
    }
  }
}

// ---------------- K4: gather key freqs + softmax weights ----------------
__global__ __launch_bounds__(64) void keygather_kernel(
    const float* __restrict__ mag, const float* __restrict__ ph, const int* __restrict__ idx,
    float* __restrict__ km, float* __restrict__ kp,
    float* __restrict__ kr, float* __restrict__ ki, float* __restrict__ wsm)
{
  int bc = blockIdx.x, t = threadIdx.x;
  int i0 = idx[t];
  int i1 = idx[64];
  float m0 = mag[(size_t)bc*LDIM + i0];
  float p0 = ph [(size_t)bc*LDIM + i0];
  float m1 = mag[(size_t)bc*LDIM + i1];
  float p1 = ph [(size_t)bc*LDIM + i1];
  size_t o = (size_t)bc*TDIM;
  km[o + t] = m0; kp[o + t] = p0;
  kr[o + t] = m0 * cosf(p0); ki[o + t] = m0 * sinf(p0);
  if (t == 0){
    km[o+64] = m1; kp[o+64] = p1;
    kr[o+64] = m1*cosf(p1); ki[o+64] = m1*sinf(p1);
  }
  // softmax over 65 key magnitudes
  float mx = wred_max(fmaxf(m0, m1));
  float e0 = expf(m0 - mx), e1 = expf(m1 - mx);
  float sum = wred_sum(e0) + e1;
  wsm[o + t] = e0 / sum;
  if (t == 0) wsm[o + 64] = e1 / sum;
}

// ---------------- K5: prob-distance + gumbel mask ----------------
__global__ __launch_bounds__(64) void distmask_kernel(
    const float* __restrict__ km, const float* __restrict__ kp,
    const float* __restrict__ A, const float* __restrict__ wAs, const float* __restrict__ wPs,
    const float* __restrict__ noise, float* __restrict__ mask)
{
  int b = blockIdx.x / TDIM, i = blockIdx.x % TDIM;
  int l = threadIdx.x;
  __shared__ float kmi[CDIM], kpi[CDIM];
  if (l < CDIM){
    kmi[l] = km[(size_t)(b*CDIM + l)*TDIM + i];
    kpi[l] = kp[(size_t)(b*CDIM + l)*TDIM + i];
  }
  __syncthreads();
  float wa = wAs[0], wp = wPs[0];
  float ed0, ed1 = 0.f;
  {
    int j = l;
    float Ad = A[j*TDIM + j];
    float acc = 0.f;
    for (int c = 0; c < CDIM; ++c){
      float d = Ad * (wa*(kmi[c] - km[(size_t)(b*CDIM+c)*TDIM + j])
                    + wp*(kpi[c] - kp[(size_t)(b*CDIM+c)*TDIM + j]));
      acc += d*d;
    }
    ed0 = (j == i) ? 0.f : 1.0f/(acc + 1e-10f);
  }
  if (l == 0){
    int j = 64;
    float Ad = A[j*TDIM + j];
    float acc = 0.f;
    for (int c = 0; c < CDIM; ++c){
      float d = Ad * (wa*(kmi[c] - km[(size_t)(b*CDIM+c)*TDIM + j])
                    + wp*(kpi[c] - kp[(size_t)(b*CDIM+c)*TDIM + j]));
      acc += d*d;
    }
    ed1 = (j == i) ? 0.f : 1.0f/(acc + 1e-10f);
  }
  float mx = ed0;
  if (l == 0) mx = fmaxf(mx, ed1);
  mx = wred_max(mx);
  // lane l -> j=l ; lane 0 also j=64
  {
    int j = l;
    float pv = (j == i) ? 0.99f : 0.99f * (ed0 / mx);
    float logit = logf(pv / (1.0f - pv));
    size_t n = ((size_t)b*TDIM + i)*TDIM + j;
    float g0 = noise[2*n], g1 = noise[2*n + 1];
    if (logit + g0 >= g1 - logit) atomicAdd(&mask[i*TDIM + j], 0.0625f);
  }
  if (l == 0){
    int j = 64;
    float pv = (j == i) ? 0.99f : 0.99f * (ed1 / mx);
    float logit = logf(pv / (1.0f - pv));
    size_t n = ((size_t)b*TDIM + i)*TDIM + j;
    float g0 = noise[2*n], g1 = noise[2*n + 1];
    if (logit + g0 >= g1 - logit) atomicAdd(&mask[i*TDIM + j], 0.0625f);
  }
}

// ---------------- K6: relationship tensor (complex sigmoid real part) ----------------
__global__ __launch_bounds__(256) void rel_kernel(
    const float* __restrict__ xr, const float* __restrict__ xi,
    const float* __restrict__ kr, const float* __restrict__ ki,
    float* __restrict__ hf, us16* __restrict__ hb)
{
  size_t e = (size_t)blockIdx.x * 256 + threadIdx.x;  // 17,039,360 exact
  int d = (int)(e & 511);
  size_t mt = e >> 9;
  int t  = (int)(mt % TDIM);
  int bc = (int)(mt / TDIM);
  float krv = kr[(size_t)bc*TDIM + t], kiv = ki[(size_t)bc*TDIM + t];
  float r = xr[(size_t)bc*LDIM + d], im = xi[(size_t)bc*LDIM + d];
  float a  = krv*r - kiv*im;
  float bb = krv*im + kiv*r;
  float ea = expf(-a);
  float sn, cs; sincosf(bb, &sn, &cs);
  float wr = 1.0f + ea*cs;
  float wi = -ea*sn;
  float rel = wr / (wr*wr + wi*wi);
  hf[e] = rel;
  hb[e] = f2bf(rel);
}

// ---------------- weight f32 -> bf16 ----------------
__global__ __launch_bounds__(256) void convert_kernel(
    const float* __restrict__ s, us16* __restrict__ d, int n)
{
  int i = blockIdx.x * 256 + threadIdx.x;
  if (i < n) d[i] = f2bf(s[i]);
}

// ---------------- GEMM: C[m,n] = sum_k X[m,k]*W[n,k] + bias[n] ----------------
// 128x128 tile, BK=32, 4 waves (2x2), mfma_f32_16x16x32_bf16.
// LDS: linear chunks, XOR slot-swizzle on both source addr and read addr (rule #21).
// EPI: 0 = store bf16 ; 1 = store f32 ; 2 = gelu -> bf16
template<int EPI>
__global__ __launch_bounds__(256) void gemm_bt(
    const us16* __restrict__ X, const us16* __restrict__ W,
    const float* __restrict__ bias,
    us16* __restrict__ outB, float* __restrict__ outF)
{
  __shared__ us16 As[128*32];
  __shared__ us16 Bs[128*32];
  const int tid = threadIdx.x;
  const int w = tid >> 6, l = tid & 63;
  const int m0 = blockIdx.x * 128, n0 = blockIdx.y * 128;
  const int wm = w >> 1, wn = w & 1;
  const int g = l >> 4, li = l & 15;
  fx4 acc[4][4] = {};

  for (int k0 = 0; k0 < 512; k0 += 32){
    #pragma unroll
    for (int q = 0; q < 2; ++q){
      int c = w*128 + q*64 + l;
      int row = c >> 2, slot = c & 3;
      int koct = (slot ^ (row & 3)) << 3;
      const us16* srcA = X + (size_t)(m0 + row)*512 + k0 + koct;
      const us16* srcB = W + (size_t)(n0 + row)*512 + k0 + koct;
      async16(&As[(w*128 + q*64)*8], srcA);
      async16(&Bs[(w*128 + q*64)*8], srcB);
    }
    __syncthreads();
    bf16x8 aF[4], bF[4];
    #pragma unroll
    for (int mi = 0; mi < 4; ++mi){
      int r = wm*64 + mi*16 + li;
      int chunk = 4*r + (g ^ (r & 3));
      aF[mi] = *reinterpret_cast<const bf16x8*>(&As[chunk*8]);
    }
    #pragma unroll
    for (int ni = 0; ni < 4; ++ni){
      int cn = wn*64 + ni*16 + li;
      int chunk = 4*cn + (g ^ (cn & 3));
      bF[ni] = *reinterpret_cast<const bf16x8*>(&Bs[chunk*8]);
    }
    #pragma unroll
    for (int mi = 0; mi < 4; ++mi)
      #pragma unroll
      for (int ni = 0; ni < 4; ++ni)
        acc[mi][ni] = __builtin_amdgcn_mfma_f32_16x16x32_bf16(aF[mi], bF[ni], acc[mi][ni], 0, 0, 0);
    __syncthreads();
  }

  // epilogue — C/D layout: col = lane&15, row = (lane>>4)*4 + reg  [m89-verified]
  #pragma unroll
  for (int mi = 0; mi < 4; ++mi){
    #pragma unroll
    for (int ni = 0; ni < 4; ++ni){
      int col = n0 + wn*64 + ni*16 + li;
      float bv = bias[col];
      #pragma unroll
      for (int r = 0; r < 4; ++r){
        int row = m0 + wm*64 + mi*16 + g*4 + r;
        float v = acc[mi][ni][r] + bv;
        if (EPI == 2) v = gelu_exact(v);
        if (EPI == 0 || EPI == 2) outB[(size_t)row*512 + col] = f2bf(v);
        else                      outF[(size_t)row*512 + col] = v;
      }
    }
  }
}

// ---------------- attention: one (batch, head) per block ----------------
#define SSTR 67
__global__ __launch_bounds__(128) void attn_kernel(
    const us16* __restrict__ qb, const us16* __restrict__ kb, const us16* __restrict__ vb,
    const float* __restrict__ mask, us16* __restrict__ ob)
{
  int bn = blockIdx.x, h = blockIdx.y;
  __shared__ float qs[TDIM*SSTR], ks[TDIM*SSTR], vs[TDIM*SSTR];
  int tid = threadIdx.x;
  for (int e = tid; e < TDIM*64; e += 128){
    int i = e >> 6, d = e & 63;
    size_t base = ((size_t)bn*TDIM + i)*512 + h*64 + d;
    qs[i*SSTR + d] = bf2f(qb[base]);
    ks[i*SSTR + d] = bf2f(kb[base]);
    vs[i*SSTR + d] = bf2f(vb[base]);
  }
  __syncthreads();
  int w = tid >> 6, l = tid & 63;
  for (int i = w; i < TDIM; i += 2){
    float s0 = 0.f, s1 = 0.f;
    for (int d = 0; d < 64; ++d){
      float q = qs[i*SSTR + d];
      s0 += q * ks[l*SSTR + d];
      s1 += q * ks[64*SSTR + d];   // key 64, broadcast (redundant across lanes)
    }
    float m0 = mask[i*TDIM + l], m1 = mask[i*TDIM + 64];
    s0 = (s0*m0 + (1.0f - m0)*(-1e9f)) * 0.125f;
    s1 = (s1*m1 + (1.0f - m1)*(-1e9f)) * 0.125f;
    float mx = wred_max(fmaxf(s0, s1));
    float e0 = expf(s0 - mx), e1 = expf(s1 - mx);
    float sum = wred_sum(e0) + e1;
    float a0 = e0 / sum, a1 = e1 / sum;
    // PV via shuffle broadcast of attention row
    float acc = 0.f;
    for (int j = 0; j < 64; ++j){
      float aj = __shfl(a0, j);
      acc += aj * vs[j*SSTR + l];
    }
    acc += a1 * vs[64*SSTR + l];
    ob[((size_t)bn*TDIM + i)*512 + h*64 + l] = f2bf(acc);
  }
}

// ---------------- layernorm (+ optional residual) ----------------
__global__ __launch_bounds__(64) void ln_kernel(
    const float* __restrict__ X, const float* __restrict__ R,
    const float* __restrict__ g, const float* __restrict__ b,
    float* __restrict__ outF, us16* __restrict__ outB)
{
  int row = blockIdx.x, l = threadIdx.x;
  const float* x = X + (size_t)row * DDIM;
  float v[8];
  #pragma unroll
  for (int e = 0; e < 8; ++e) v[e] = x[l*8 + e];
  if (R){
    const float* r = R + (size_t)row * DDIM;
    #pragma unroll
    for (int e = 0; e < 8; ++e) v[e] += r[l*8 + e];
  }
  float s = 0.f;
  #pragma unroll
  for (int e = 0; e < 8; ++e) s += v[e];
  float mu = wred_sum(s) * (1.0f/512.0f);
  float qq = 0.f;
  #pragma unroll
  for (int e = 0; e < 8; ++e){ float d = v[e] - mu; qq += d*d; }
  float var = wred_sum(qq) * (1.0f/512.0f);
  float inv = 1.0f / sqrtf(var + LN_EPS);
  #pragma unroll
  for (int e = 0; e < 8; ++e){
    int c = l*8 + e;
    float y = (v[e] - mu) * inv * g[c] + b[c];
    if (outF) outF[(size_t)row*DDIM + c] = y;
    if (outB) outB[(size_t)row*DDIM + c] = f2bf(y);
  }
}

// ---------------- final weighted sum + polar ----------------
__global__ __launch_bounds__(512) void final_kernel(
    const float* __restrict__ hfin, const float* __restrict__ wsm,
    const float* __restrict__ ph, float* __restrict__ out)
{
  int bc = blockIdx.x, d = threadIdx.x;
  __shared__ float wv[TDIM];
  if (d < TDIM) wv[d] = wsm[(size_t)bc*TDIM + d];
  __syncthreads();
  float fs = 0.f;
  for (int t = 0; t < TDIM; ++t)
    fs += hfin[((size_t)bc*TDIM + t)*DDIM + d] * wv[t];
  float p = ph[(size_t)bc*LDIM + d];
  float sn, cs; sincosf(p, &sn, &cs);
  out[((size_t)bc*LDIM + d)*2 + 0] = fs * cs;
  out[((size_t)bc*LDIM + d)*2 + 1] = fs * sn;
}

// ---------------- launch ----------------
extern "C" void kernel_launch(void* const* d_in, const int* in_sizes, int n_in,
                              void* d_out, int out_size, void* d_ws, size_t ws_size,
                              hipStream_t stream)
{
  const float* xr    = (const float*)d_in[0];
  const float* xi    = (const float*)d_in[1];
  const float* noise = (const float*)d_in[2];
  const float* Amat  = (const float*)d_in[3];
  const float* wA    = (const float*)d_in[4];
  const float* wP    = (const float*)d_in[5];
  const float* Wq    = (const float*)d_in[6];
  const float* bq    = (const float*)d_in[7];
  const float* Wk    = (const float*)d_in[8];
  const float* bk    = (const float*)d_in[9];
  const float* Wv    = (const float*)d_in[10];
  const float* bv    = (const float*)d_in[11];
  const float* Wo    = (const float*)d_in[12];
  const float* bo    = (const float*)d_in[13];
  const float* Wc1   = (const float*)d_in[14];
  const float* bc1   = (const float*)d_in[15];
  const float* Wc2   = (const float*)d_in[16];
  const float* bc2   = (const float*)d_in[17];
  const float* g1    = (const float*)d_in[18];
  const float* b1    = (const float*)d_in[19];
  const float* g2    = (const float*)d_in[20];
  const float* b2    = (const float*)d_in[21];
  const float* gf    = (const float*)d_in[22];
  const float* bfin  = (const float*)d_in[23];
  float* out = (float*)d_out;

  char* p = (char*)d_ws;
  auto take = [&](size_t bytes) -> char* {
    char* r = p; p += (bytes + 255) & ~(size_t)255; return r;
  };
  float*  mag  = (float*)take((size_t)BC*LDIM*4);
  float*  ph   = (float*)take((size_t)BC*LDIM*4);
  double* gm   = (double*)take(LDIM*8);
  int*    idx  = (int*)take(TDIM*4);
  float*  km   = (float*)take((size_t)BC*TDIM*4);
  float*  kp   = (float*)take((size_t)BC*TDIM*4);
  float*  kr   = (float*)take((size_t)BC*TDIM*4);
  float*  ki   = (float*)take((size_t)BC*TDIM*4);
  float*  wsm  = (float*)take((size_t)BC*TDIM*4);
  float*  mask = (float*)take(TDIM*TDIM*4);
  us16*   wbf  = (us16*)take((size_t)6*2*DDIM*DDIM*2);
  float*  hf   = (float*)take((size_t)MROWS*DDIM*4);
  us16*   hb   = (us16*)take((size_t)MROWS*DDIM*2);
  us16*   qb   = (us16*)take((size_t)MROWS*DDIM*2);
  us16*   kb2  = (us16*)take((size_t)MROWS*DDIM*2);
  us16*   vb2  = (us16*)take((size_t)MROWS*DDIM*2);
  us16*   ob   = (us16*)take((size_t)MROWS*DDIM*2);
  float*  t0   = (float*)kb2;   // aliases kb2+vb2 (contiguous 68 MB) — lifetimes disjoint via stream order
  us16*   yb   = qb;            // alias — qb dead after attention

  magph_kernel<<<dim3(1024), dim3(256), 0, stream>>>(xr, xi, mag, ph);
  gm_kernel<<<dim3(LDIM), dim3(64), 0, stream>>>(mag, gm);
  topk_kernel<<<dim3(1), dim3(64), 0, stream>>>(gm, idx);
  keygather_kernel<<<dim3(BC), dim3(64), 0, stream>>>(mag, ph, idx, km, kp, kr, ki, wsm);
  hipMemsetAsync(mask, 0, TDIM*TDIM*4, stream);
  distmask_kernel<<<dim3(BDIM*TDIM), dim3(64), 0, stream>>>(km, kp, Amat, wA, wP, noise, mask);
  rel_kernel<<<dim3(66560), dim3(256), 0, stream>>>(xr, xi, kr, ki, hf, hb);

  const float* Wsrc[6] = {Wq, Wk, Wv, Wo, Wc1, Wc2};
  for (int m = 0; m < 6; ++m)
    convert_kernel<<<dim3(2048), dim3(256), 0, stream>>>(
        Wsrc[m], wbf + (size_t)m*2*DDIM*DDIM, 2*DDIM*DDIM);

  dim3 ggrid(MROWS/128, DDIM/128);
  for (int l = 0; l < 2; ++l){
    const us16* wq_  = wbf + ((size_t)0*2 + l)*DDIM*DDIM;
    const us16* wk_  = wbf + ((size_t)1*2 + l)*DDIM*DDIM;
    const us16* wv_  = wbf + ((size_t)2*2 + l)*DDIM*DDIM;
    const us16* wo_  = wbf + ((size_t)3*2 + l)*DDIM*DDIM;
    const us16* wc1_ = wbf + ((size_t)4*2 + l)*DDIM*DDIM;
    const us16* wc2_ = wbf + ((size_t)5*2 + l)*DDIM*DDIM;

    gemm_bt<0><<<ggrid, 256, 0, stream>>>(hb, wq_, bq + (size_t)l*DDIM, qb,  nullptr);
    gemm_bt<0><<<ggrid, 256, 0, stream>>>(hb, wk_, bk + (size_t)l*DDIM, kb2, nullptr);
    gemm_bt<0><<<ggrid, 256, 0, stream>>>(hb, wv_, bv + (size_t)l*DDIM, vb2, nullptr);
    attn_kernel<<<dim3(BC, 8), dim3(128), 0, stream>>>(qb, kb2, vb2, mask, ob);
    gemm_bt<1><<<ggrid, 256, 0, stream>>>(ob, wo_, bo + (size_t)l*DDIM, nullptr, t0);
    ln_kernel<<<dim3(MROWS), dim3(64), 0, stream>>>(hf, t0, g1 + (size_t)l*DDIM, b1 + (size_t)l*DDIM, hf, hb);
    gemm_bt<2><<<ggrid, 256, 0, stream>>>(hb, wc1_, bc1 + (size_t)l*DDIM, yb, nullptr);
    gemm_bt<1><<<ggrid, 256, 0, stream>>>(yb, wc2_, bc2 + (size_t)l*DDIM, nullptr, t0);
    ln_kernel<<<dim3(MROWS), dim3(64), 0, stream>>>(hf, t0, g2 + (size_t)l*DDIM, b2 + (size_t)l*DDIM, hf, hb);
  }
  ln_kernel<<<dim3(MROWS), dim3(64), 0, stream>>>(hf, nullptr, gf, bfin, t0, nullptr);
  final_kernel<<<dim3(BC), dim3(512), 0, stream>>>(t0, wsm, ph, out);
}

// Round 3
// 1244.168 us; speedup vs baseline: 2.1199x; 2.1199x over previous
//
#include <hip/hip_runtime.h>
#include <hip/hip_bf16.h>

// ---------------- static problem config ----------------
#define BDIM 16
#define CDIM 32
#define LDIM 512
#define TDIM 65            // all_topk
#define DDIM 512
#define BC   (BDIM*CDIM)   // 512
#define MROWS (BC*TDIM)    // 33280
#define LN_EPS 1e-5f

typedef float fx4 __attribute__((ext_vector_type(4)));
typedef __bf16 bf16x8 __attribute__((ext_vector_type(8)));
typedef unsigned short us16;

// ---------------- helpers ----------------
__device__ __forceinline__ us16 f2bf(float f){
  unsigned int u = __float_as_uint(f);
  u = (u + 0x7fffu + ((u >> 16) & 1u)) >> 16;
  return (us16)u;
}
__device__ __forceinline__ float bf2f(us16 s){
  return __uint_as_float(((unsigned int)s) << 16);
}
__device__ __forceinline__ float wred_max(float v){
  #pragma unroll
  for (int o = 32; o; o >>= 1) v = fmaxf(v, __shfl_xor(v, o));
  return v;
}
__device__ __forceinline__ float wred_sum(float v){
  #pragma unroll
  for (int o = 32; o; o >>= 1) v += __shfl_xor(v, o);
  return v;
}
__device__ __forceinline__ float gelu_exact(float x){
  return 0.5f * x * (1.0f + erff(x * 0.70710678118654752440f));
}
__device__ __forceinline__ void async16(void* lds, const void* g){
  __builtin_amdgcn_global_load_lds(
      (const __attribute__((address_space(1))) unsigned int*)g,
      (__attribute__((address_space(3))) unsigned int*)lds, 16, 0, 0);
}

// ---------------- K1: magnitude / phase ----------------
__global__ __launch_bounds__(256) void magph_kernel(
    const float* __restrict__ xr, const float* __restrict__ xi,
    float* __restrict__ mag, float* __restrict__ ph)
{
  int i = blockIdx.x * 256 + threadIdx.x;   // n = 262144 exact
  float r = xr[i], im = xi[i];
  mag[i] = sqrtf(r*r + im*im);
  ph[i]  = atan2f(im, r);
}

// ---------------- K2: per-frequency energy (double accum) ----------------
__global__ __launch_bounds__(64) void gm_kernel(
    const float* __restrict__ mag, double* __restrict__ gm)
{
  int l = blockIdx.x, t = threadIdx.x;
  double acc = 0.0;
  #pragma unroll
  for (int r = 0; r < 8; ++r){
    float v = mag[(size_t)(t + 64*r)*LDIM + l];
    acc += (double)v * (double)v;
  }
  #pragma unroll
  for (int o = 32; o; o >>= 1) acc += __shfl_xor(acc, o);
  if (t == 0) gm[l] = acc;
}

// ---------------- K3: top-k index selection ----------------
__device__ int wave_argmax(const float* val, int lo, int hi, int t){
  float bv = -3.4e38f; int bi = 0x7fffffff;
  for (int i = lo + t; i < hi; i += 64){
    float v = val[i];
    if (v > bv || (v == bv && i < bi)){ bv = v; bi = i; }
  }
  #pragma unroll
  for (int o = 32; o; o >>= 1){
    float ov = __shfl_xor(bv, o); int oi = __shfl_xor(bi, o);
    if (ov > bv || (ov == bv && oi < bi)){ bv = ov; bi = oi; }
  }
  return bi;
}

__global__ __launch_bounds__(64) void topk_kernel(
    const double* __restrict__ gm, int* __restrict__ idxo)
{
  __shared__ float val[LDIM];
  __shared__ float orig[LDIM];
  int t = threadIdx.x;
  for (int i = t; i < LDIM; i += 64){ float v = (float)gm[i]; val[i] = v; orig[i] = v; }
  __syncthreads();
  // global top-32 (argsort(-gm), stable ties -> smaller index)
  for (int s = 0; s < 32; ++s){
    int b = wave_argmax(val, 0, LDIM, t);
    if (t == 0){ idxo[s] = b; val[b] = -3.4e38f; }
    __syncthreads();
  }
  for (int i = t; i < LDIM; i += 64) val[i] = orig[i];
  __syncthreads();
  // 3 bands x top-11
  for (int bb = 0; bb < 3; ++bb){
    int s0 = bb*170, e0 = (bb == 2) ? LDIM : (bb+1)*170;
    for (int s = 0; s < 11; ++s){
      int b = wave_argmax(val, s0, e0, t);
      if (t == 0){ idxo[32 + bb*11 + s] = b; val[b] = -3.4e38f; }
      __syncthreads();
    }
  }
}

// ---------------- K4: gather key freqs + softmax weights ----------------
__global__ __launch_bounds__(64) void keygather_kernel(
    const float* __restrict__ mag, const float* __restrict__ ph, const int* __restrict__ idx,
    float* __restrict__ km, float* __restrict__ kp,
    float* __restrict__ kr, float* __restrict__ ki, float* __restrict__ wsm)
{
  int bc = blockIdx.x, t = threadIdx.x;
  int i0 = idx[t];
  int i1 = idx[64];
  float m0 = mag[(size_t)bc*LDIM + i0];
  float p0 = ph [(size_t)bc*LDIM + i0];
  float m1 = mag[(size_t)bc*LDIM + i1];
  float p1 = ph [(size_t)bc*LDIM + i1];
  size_t o = (size_t)bc*TDIM;
  km[o + t] = m0; kp[o + t] = p0;
  kr[o + t] = m0 * cosf(p0); ki[o + t] = m0 * sinf(p0);
  if (t == 0){
    km[o+64] = m1; kp[o+64] = p1;
    kr[o+64] = m1*cosf(p1); ki[o+64] = m1*sinf(p1);
  }
  // softmax over 65 key magnitudes
  float mx = wred_max(fmaxf(m0, m1));
  float e0 = expf(m0 - mx), e1 = expf(m1 - mx);
  float sum = wred_sum(e0) + e1;
  wsm[o + t] = e0 / sum;
  if (t == 0) wsm[o + 64] = e1 / sum;
}

// ---------------- K5: prob-distance + gumbel mask ----------------
__global__ __launch_bounds__(64) void distmask_kernel(
    const float* __restrict__ km, const float* __restrict__ kp,
    const float* __restrict__ A, const float* __restrict__ wAs, const float* __restrict__ wPs,
    const float* __restrict__ noise, float* __restrict__ mask)
{
  int b = blockIdx.x / TDIM, i = blockIdx.x % TDIM;
  int l = threadIdx.x;
  __shared__ float kmi[CDIM], kpi[CDIM];
  if (l < CDIM){
    kmi[l] = km[(size_t)(b*CDIM + l)*TDIM + i];
    kpi[l] = kp[(size_t)(b*CDIM + l)*TDIM + i];
  }
  __syncthreads();
  float wa = wAs[0], wp = wPs[0];
  float ed0, ed1 = 0.f;
  {
    int j = l;
    float Ad = A[j*TDIM + j];
    float acc = 0.f;
    for (int c = 0; c < CDIM; ++c){
      float d = Ad * (wa*(kmi[c] - km[(size_t)(b*CDIM+c)*TDIM + j])
                    + wp*(kpi[c] - kp[(size_t)(b*CDIM+c)*TDIM + j]));
      acc += d*d;
    }
    ed0 = (j == i) ? 0.f : 1.0f/(acc + 1e-10f);
  }
  if (l == 0){
    int j = 64;
    float Ad = A[j*TDIM + j];
    float acc = 0.f;
    for (int c = 0; c < CDIM; ++c){
      float d = Ad * (wa*(kmi[c] - km[(size_t)(b*CDIM+c)*TDIM + j])
                    + wp*(kpi[c] - kp[(size_t)(b*CDIM+c)*TDIM + j]));
      acc += d*d;
    }
    ed1 = (j == i) ? 0.f : 1.0f/(acc + 1e-10f);
  }
  float mx = ed0;
  if (l == 0) mx = fmaxf(mx, ed1);
  mx = wred_max(mx);
  // lane l -> j=l ; lane 0 also j=64
  {
    int j = l;
    float pv = (j == i) ? 0.99f : 0.99f * (ed0 / mx);
    float logit = logf(pv / (1.0f - pv));
    size_t n = ((size_t)b*TDIM + i)*TDIM + j;
    float g0 = noise[2*n], g1 = noise[2*n + 1];
    if (logit + g0 >= g1 - logit) atomicAdd(&mask[i*TDIM + j], 0.0625f);
  }
  if (l == 0){
    int j = 64;
    float pv = (j == i) ? 0.99f : 0.99f * (ed1 / mx);
    float logit = logf(pv / (1.0f - pv));
    size_t n = ((size_t)b*TDIM + i)*TDIM + j;
    float g0 = noise[2*n], g1 = noise[2*n + 1];
    if (logit + g0 >= g1 - logit) atomicAdd(&mask[i*TDIM + j], 0.0625f);
  }
}

// ---------------- K6: relationship tensor (complex sigmoid real part) ----------------
__global__ __launch_bounds__(256) void rel_kernel(
    const float* __restrict__ xr, const float* __restrict__ xi,
    const float* __restrict__ kr, const float* __restrict__ ki,
    float* __restrict__ hf, us16* __restrict__ hb)
{
  size_t e = (size_t)blockIdx.x * 256 + threadIdx.x;  // 17,039,360 exact
  int d = (int)(e & 511);
  size_t mt = e >> 9;
  int t  = (int)(mt % TDIM);
  int bc = (int)(mt / TDIM);
  float krv = kr[(size_t)bc*TDIM + t], kiv = ki[(size_t)bc*TDIM + t];
  float r = xr[(size_t)bc*LDIM + d], im = xi[(size_t)bc*LDIM + d];
  float a  = krv*r - kiv*im;
  float bb = krv*im + kiv*r;
  float ea = expf(-a);
  float sn, cs; sincosf(bb, &sn, &cs);
  float wr = 1.0f + ea*cs;
  float wi = -ea*sn;
  float rel = wr / (wr*wr + wi*wi);
  hf[e] = rel;
  hb[e] = f2bf(rel);
}

// ---------------- weight f32 -> bf16 ----------------
__global__ __launch_bounds__(256) void convert_kernel(
    const float* __restrict__ s, us16* __restrict__ d, int n)
{
  int i = blockIdx.x * 256 + threadIdx.x;
  if (i < n) d[i] = f2bf(s[i]);
}

// ---------------- GEMM: C[m,n] = sum_k X[m,k]*W[n,k] + bias[n] ----------------
// 128x128 tile, BK=32, 4 waves (2x2), mfma_f32_16x16x32_bf16.
// LDS: linear chunks, XOR slot-swizzle on both source addr and read addr (rule #21).
// EPI: 0 = store bf16 ; 1 = store f32 ; 2 = gelu -> bf16
template<int EPI>
__global__ __launch_bounds__(256) void gemm_bt(
    const us16* __restrict__ X, const us16* __restrict__ W,
    const float* __restrict__ bias,
    us16* __restrict__ outB, float* __restrict__ outF)
{
  __shared__ us16 As[128*32];
  __shared__ us16 Bs[128*32];
  const int tid = threadIdx.x;
  const int w = tid >> 6, l = tid & 63;
  const int m0 = blockIdx.x * 128, n0 = blockIdx.y * 128;
  const int wm = w >> 1, wn = w & 1;
  const int g = l >> 4, li = l & 15;
  fx4 acc[4][4] = {};

  for (int k0 = 0; k0 < 512; k0 += 32){
    #pragma unroll
    for (int q = 0; q < 2; ++q){
      int c = w*128 + q*64 + l;
      int row = c >> 2, slot = c & 3;
      int koct = (slot ^ (row & 3)) << 3;
      const us16* srcA = X + (size_t)(m0 + row)*512 + k0 + koct;
      const us16* srcB = W + (size_t)(n0 + row)*512 + k0 + koct;
      async16(&As[(w*128 + q*64)*8], srcA);
      async16(&Bs[(w*128 + q*64)*8], srcB);
    }
    __syncthreads();
    bf16x8 aF[4], bF[4];
    #pragma unroll
    for (int mi = 0; mi < 4; ++mi){
      int r = wm*64 + mi*16 + li;
      int chunk = 4*r + (g ^ (r & 3));
      aF[mi] = *reinterpret_cast<const bf16x8*>(&As[chunk*8]);
    }
    #pragma unroll
    for (int ni = 0; ni < 4; ++ni){
      int cn = wn*64 + ni*16 + li;
      int chunk = 4*cn + (g ^ (cn & 3));
      bF[ni] = *reinterpret_cast<const bf16x8*>(&Bs[chunk*8]);
    }
    #pragma unroll
    for (int mi = 0; mi < 4; ++mi)
      #pragma unroll
      for (int ni = 0; ni < 4; ++ni)
        acc[mi][ni] = __builtin_amdgcn_mfma_f32_16x16x32_bf16(aF[mi], bF[ni], acc[mi][ni], 0, 0, 0);
    __syncthreads();
  }

  // epilogue — C/D layout: col = lane&15, row = (lane>>4)*4 + reg  [m89-verified]
  #pragma unroll
  for (int mi = 0; mi < 4; ++mi){
    #pragma unroll
    for (int ni = 0; ni < 4; ++ni){
      int col = n0 + wn*64 + ni*16 + li;
      float bv = bias[col];
      #pragma unroll
      for (int r = 0; r < 4; ++r){
        int row = m0 + wm*64 + mi*16 + g*4 + r;
        float v = acc[mi][ni][r] + bv;
        if (EPI == 2) v = gelu_exact(v);
        if (EPI == 0 || EPI == 2) outB[(size_t)row*512 + col] = f2bf(v);
        else                      outF[(size_t)row*512 + col] = v;
      }
    }
  }
}

// ---------------- attention v2: MFMA flash-style, one (bn,h) per 256-thr block ----
// Qs/Ks: [80][64] bf16, 8x16B slots/row, slot XOR-swizzled by (row&7). Rows 65..79
// of Qs/Ks are never written (garbage affects only discarded pad rows / masked
// cols, never touched by the valid-j path). Vt: V transposed [d][k], [64][96],
// cols 65..95 zeroed. Pb: P bf16 [80][96], cols 80..95 zeroed. Split swizzle for
// 12-slot rows: s<8 -> s^(r&7); s>=8 -> 8+((s&3)^(r&3)).
__global__ __launch_bounds__(256) void attn_mfma(
    const us16* __restrict__ qb, const us16* __restrict__ kb, const us16* __restrict__ vb,
    const float* __restrict__ mask, us16* __restrict__ ob)
{
  __shared__ __align__(16) us16 Qs[80*64];
  __shared__ __align__(16) us16 Ks[80*64];
  __shared__ __align__(16) us16 Vt[64*96];
  __shared__ __align__(16) us16 Pb[80*96];
  const int bn = blockIdx.x, h = blockIdx.y;
  const int tid = threadIdx.x;
  const int w = tid >> 6, l = tid & 63;
  const int g = l >> 4, li = l & 15;
  const size_t gbase = ((size_t)bn*TDIM)*512 + h*64;

  // ---- phase A: zero Vt/Pb, async-stage Q/K rows 0..63, reg-load V + row 64 ----
  {
    uint2 z = {0u, 0u};
    for (int u = tid; u < 1536; u += 256) ((uint2*)Vt)[u] = z;   // 12 KB
    for (int u = tid; u < 1920; u += 256) ((uint2*)Pb)[u] = z;   // 15 KB
  }
  #pragma unroll
  for (int it = 0; it < 2; ++it){
    int u = it*256 + tid;           // 0..511  -> rows 0..63, 8 slots each
    int r = u >> 3, ps = u & 7;
    int slog = ps ^ (r & 7);        // involution: phys slot ps holds logical octet slog
    async16(&Qs[(it*256 + w*64)*8], qb + gbase + (size_t)r*512 + slog*8);
    async16(&Ks[(it*256 + w*64)*8], kb + gbase + (size_t)r*512 + slog*8);
  }
  us16 vreg[17];
  #pragma unroll
  for (int i = 0; i < 17; ++i){
    int k = i*4 + w;
    if (k <= 64) vreg[i] = vb[gbase + (size_t)k*512 + l];
  }
  uint4 r64 = {};
  if (tid < 8)       r64 = *(const uint4*)(qb + gbase + (size_t)64*512 + tid*8);
  else if (tid < 16) r64 = *(const uint4*)(kb + gbase + (size_t)64*512 + (tid-8)*8);

  __syncthreads();   // drains vmcnt+lgkm: Q/K rows 0..63 staged, zeros done, regs ready

  // ---- phase C: Q/K row 64 + transposed V writes ----
  if (tid < 8)       *(uint4*)&Qs[(64*8 + tid)*8] = r64;     // row 64: r&7==0 -> linear
  else if (tid < 16) *(uint4*)&Ks[(64*8 + (tid-8))*8] = r64;
  #pragma unroll
  for (int i = 0; i < 17; ++i){
    int k = i*4 + w;
    if (k <= 64){
      int d = l, s = k >> 3;
      int ps = (s < 8) ? (s ^ (d & 7)) : (8 + ((s & 3) ^ (d & 3)));
      Vt[d*96 + ps*8 + (k & 7)] = vreg[i];
    }
  }
  __syncthreads();   // Vt + row64 visible to all waves

  // ---- per-wave M-tiles: wave w -> {w} (+{4} for wave 0). No barriers below. ----
  for (int m = w; m < 5; m += 4){
    const int mbase = m*16;
    // QK^T: S[i][j] = sum_k Q[i][k] K[j][k]
    fx4 acc[5] = {};
    #pragma unroll
    for (int kk = 0; kk < 2; ++kk){
      int ra = mbase + li;
      int sA = (kk*4 + g) ^ (ra & 7);
      bf16x8 aF = *(const bf16x8*)&Qs[ra*64 + sA*8];
      #pragma unroll
      for (int n = 0; n < 5; ++n){
        int rb = n*16 + li;
        int sB = (kk*4 + g) ^ (rb & 7);
        bf16x8 bF = *(const bf16x8*)&Ks[rb*64 + sB*8];
        acc[n] = __builtin_amdgcn_mfma_f32_16x16x32_bf16(aF, bF, acc[n], 0, 0, 0);
      }
    }
    // masked softmax; C layout: col = n*16+li, row = mbase + g*4 + reg
    float p[5][4];
    #pragma unroll
    for (int reg = 0; reg < 4; ++reg){
      int i = mbase + g*4 + reg;
      float sv[5], mx = -3.4e38f;
      #pragma unroll
      for (int n = 0; n < 5; ++n){
        int j = n*16 + li;
        if (j < TDIM){
          float mv = (i < TDIM) ? mask[i*TDIM + j] : 0.0f;
          sv[n] = (acc[n][reg]*mv + (1.0f - mv)*(-1e9f)) * 0.125f;
        } else sv[n] = -3.4e38f;              // excluded; never touches garbage scores
        mx = fmaxf(mx, sv[n]);
      }
      #pragma unroll
      for (int o = 1; o < 16; o <<= 1) mx = fmaxf(mx, __shfl_xor(mx, o));
      float sum = 0.f;
      #pragma unroll
      for (int n = 0; n < 5; ++n){
        int j = n*16 + li;
        float e = (j < TDIM) ? expf(sv[n] - mx) : 0.0f;
        p[n][reg] = e; sum += e;
      }
      #pragma unroll
      for (int o = 1; o < 16; o <<= 1) sum += __shfl_xor(sum, o);
      float inv = 1.0f / sum;
      #pragma unroll
      for (int n = 0; n < 5; ++n) p[n][reg] *= inv;
    }
    // write P -> Pb bf16 (own rows only; within-wave producer/consumer)
    #pragma unroll
    for (int n = 0; n < 5; ++n){
      int j = n*16 + li, s = j >> 3, jo = j & 7;
      #pragma unroll
      for (int reg = 0; reg < 4; ++reg){
        int r = mbase + g*4 + reg;
        int ps = (s < 8) ? (s ^ (r & 7)) : (8 + ((s & 3) ^ (r & 3)));
        Pb[r*96 + ps*8 + jo] = f2bf(p[n][reg]);
      }
    }
    asm volatile("s_waitcnt lgkmcnt(0)" ::: "memory");  // P writes landed before reads
    // PV: O[i][d] = sum_j P[i][j] V[j][d]  (A=P from Pb, B=V^T from Vt)
    fx4 acc2[4] = {};
    #pragma unroll
    for (int kk = 0; kk < 3; ++kk){
      int ra = mbase + li;
      int s = kk*4 + g;
      int psA = (s < 8) ? (s ^ (ra & 7)) : (8 + ((s & 3) ^ (ra & 3)));
      bf16x8 pF = *(const bf16x8*)&Pb[ra*96 + psA*8];
      #pragma unroll
      for (int n2 = 0; n2 < 4; ++n2){
        int d = n2*16 + li;
        int psB = (s < 8) ? (s ^ (d & 7)) : (8 + ((s & 3) ^ (d & 3)));
        bf16x8 vF = *(const bf16x8*)&Vt[d*96 + psB*8];
        acc2[n2] = __builtin_amdgcn_mfma_f32_16x16x32_bf16(pF, vF, acc2[n2], 0, 0, 0);
      }
    }
    // store O rows < 65
    #pragma unroll
    for (int n2 = 0; n2 < 4; ++n2){
      int d = n2*16 + li;
      #pragma unroll
      for (int reg = 0; reg < 4; ++reg){
        int i = mbase + g*4 + reg;
        if (i < TDIM) ob[gbase + (size_t)i*512 + d] = f2bf(acc2[n2][reg]);
      }
    }
  }
}

// ---------------- layernorm (+ optional residual) ----------------
__global__ __launch_bounds__(64) void ln_kernel(
    const float* __restrict__ X, const float* __restrict__ R,
    const float* __restrict__ g, const float* __restrict__ b,
    float* __restrict__ outF, us16* __restrict__ outB)
{
  int row = blockIdx.x, l = threadIdx.x;
  const float* x = X + (size_t)row * DDIM;
  float v[8];
  #pragma unroll
  for (int e = 0; e < 8; ++e) v[e] = x[l*8 + e];
  if (R){
    const float* r = R + (size_t)row * DDIM;
    #pragma unroll
    for (int e = 0; e < 8; ++e) v[e] += r[l*8 + e];
  }
  float s = 0.f;
  #pragma unroll
  for (int e = 0; e < 8; ++e) s += v[e];
  float mu = wred_sum(s) * (1.0f/512.0f);
  float qq = 0.f;
  #pragma unroll
  for (int e = 0; e < 8; ++e){ float d = v[e] - mu; qq += d*d; }
  float var = wred_sum(qq) * (1.0f/512.0f);
  float inv = 1.0f / sqrtf(var + LN_EPS);
  #pragma unroll
  for (int e = 0; e < 8; ++e){
    int c = l*8 + e;
    float y = (v[e] - mu) * inv * g[c] + b[c];
    if (outF) outF[(size_t)row*DDIM + c] = y;
    if (outB) outB[(size_t)row*DDIM + c] = f2bf(y);
  }
}

// ---------------- final weighted sum + polar ----------------
__global__ __launch_bounds__(512) void final_kernel(
    const float* __restrict__ hfin, const float* __restrict__ wsm,
    const float* __restrict__ ph, float* __restrict__ out)
{
  int bc = blockIdx.x, d = threadIdx.x;
  __shared__ float wv[TDIM];
  if (d < TDIM) wv[d] = wsm[(size_t)bc*TDIM + d];
  __syncthreads();
  float fs = 0.f;
  for (int t = 0; t < TDIM; ++t)
    fs += hfin[((size_t)bc*TDIM + t)*DDIM + d] * wv[t];
  float p = ph[(size_t)bc*LDIM + d];
  float sn, cs; sincosf(p, &sn, &cs);
  out[((size_t)bc*LDIM + d)*2 + 0] = fs * cs;
  out[((size_t)bc*LDIM + d)*2 + 1] = fs * sn;
}

// ---------------- launch ----------------
extern "C" void kernel_launch(void* const* d_in, const int* in_sizes, int n_in,
                              void* d_out, int out_size, void* d_ws, size_t ws_size,
                              hipStream_t stream)
{
  const float* xr    = (const float*)d_in[0];
  const float* xi    = (const float*)d_in[1];
  const float* noise = (const float*)d_in[2];
  const float* Amat  = (const float*)d_in[3];
  const float* wA    = (const float*)d_in[4];
  const float* wP    = (const float*)d_in[5];
  const float* Wq    = (const float*)d_in[6];
  const float* bq    = (const float*)d_in[7];
  const float* Wk    = (const float*)d_in[8];
  const float* bk    = (const float*)d_in[9];
  const float* Wv    = (const float*)d_in[10];
  const float* bv    = (const float*)d_in[11];
  const float* Wo    = (const float*)d_in[12];
  const float* bo    = (const float*)d_in[13];
  const float* Wc1   = (const float*)d_in[14];
  const float* bc1   = (const float*)d_in[15];
  const float* Wc2   = (const float*)d_in[16];
  const float* bc2   = (const float*)d_in[17];
  const float* g1    = (const float*)d_in[18];
  const float* b1    = (const float*)d_in[19];
  const float* g2    = (const float*)d_in[20];
  const float* b2    = (const float*)d_in[21];
  const float* gf    = (const float*)d_in[22];
  const float* bfin  = (const float*)d_in[23];
  float* out = (float*)d_out;

  char* p = (char*)d_ws;
  auto take = [&](size_t bytes) -> char* {
    char* r = p; p += (bytes + 255) & ~(size_t)255; return r;
  };
  float*  mag  = (float*)take((size_t)BC*LDIM*4);
  float*  ph   = (float*)take((size_t)BC*LDIM*4);
  double* gm   = (double*)take(LDIM*8);
  int*    idx  = (int*)take(TDIM*4);
  float*  km   = (float*)take((size_t)BC*TDIM*4);
  float*  kp   = (float*)take((size_t)BC*TDIM*4);
  float*  kr   = (float*)take((size_t)BC*TDIM*4);
  float*  ki   = (float*)take((size_t)BC*TDIM*4);
  float*  wsm  = (float*)take((size_t)BC*TDIM*4);
  float*  mask = (float*)take(TDIM*TDIM*4);
  us16*   wbf  = (us16*)take((size_t)6*2*DDIM*DDIM*2);
  float*  hf   = (float*)take((size_t)MROWS*DDIM*4);
  us16*   hb   = (us16*)take((size_t)MROWS*DDIM*2);
  us16*   qb   = (us16*)take((size_t)MROWS*DDIM*2);
  us16*   kb2  = (us16*)take((size_t)MROWS*DDIM*2);
  us16*   vb2  = (us16*)take((size_t)MROWS*DDIM*2);
  us16*   ob   = (us16*)take((size_t)MROWS*DDIM*2);
  float*  t0   = (float*)kb2;   // aliases kb2+vb2 (contiguous 68 MB) — lifetimes disjoint via stream order
  us16*   yb   = qb;            // alias — qb dead after attention

  magph_kernel<<<dim3(1024), dim3(256), 0, stream>>>(xr, xi, mag, ph);
  gm_kernel<<<dim3(LDIM), dim3(64), 0, stream>>>(mag, gm);
  topk_kernel<<<dim3(1), dim3(64), 0, stream>>>(gm, idx);
  keygather_kernel<<<dim3(BC), dim3(64), 0, stream>>>(mag, ph, idx, km, kp, kr, ki, wsm);
  hipMemsetAsync(mask, 0, TDIM*TDIM*4, stream);
  distmask_kernel<<<dim3(BDIM*TDIM), dim3(64), 0, stream>>>(km, kp, Amat, wA, wP, noise, mask);
  rel_kernel<<<dim3(66560), dim3(256), 0, stream>>>(xr, xi, kr, ki, hf, hb);

  const float* Wsrc[6] = {Wq, Wk, Wv, Wo, Wc1, Wc2};
  for (int m = 0; m < 6; ++m)
    convert_kernel<<<dim3(2048), dim3(256), 0, stream>>>(
        Wsrc[m], wbf + (size_t)m*2*DDIM*DDIM, 2*DDIM*DDIM);

  dim3 ggrid(MROWS/128, DDIM/128);
  for (int l = 0; l < 2; ++l){
    const us16* wq_  = wbf + ((size_t)0*2 + l)*DDIM*DDIM;
    const us16* wk_  = wbf + ((size_t)1*2 + l)*DDIM*DDIM;
    const us16* wv_  = wbf + ((size_t)2*2 + l)*DDIM*DDIM;
    const us16* wo_  = wbf + ((size_t)3*2 + l)*DDIM*DDIM;
    const us16* wc1_ = wbf + ((size_t)4*2 + l)*DDIM*DDIM;
    const us16* wc2_ = wbf + ((size_t)5*2 + l)*DDIM*DDIM;

    gemm_bt<0><<<ggrid, 256, 0, stream>>>(hb, wq_, bq + (size_t)l*DDIM, qb,  nullptr);
    gemm_bt<0><<<ggrid, 256, 0, stream>>>(hb, wk_, bk + (size_t)l*DDIM, kb2, nullptr);
    gemm_bt<0><<<ggrid, 256, 0, stream>>>(hb, wv_, bv + (size_t)l*DDIM, vb2, nullptr);
    attn_mfma<<<dim3(BC, 8), dim3(256), 0, stream>>>(qb, kb2, vb2, mask, ob);
    gemm_bt<1><<<ggrid, 256, 0, stream>>>(ob, wo_, bo + (size_t)l*DDIM, nullptr, t0);
    ln_kernel<<<dim3(MROWS), dim3(64), 0, stream>>>(hf, t0, g1 + (size_t)l*DDIM, b1 + (size_t)l*DDIM, hf, hb);
    gemm_bt<2><<<ggrid, 256, 0, stream>>>(hb, wc1_, bc1 + (size_t)l*DDIM, yb, nullptr);
    gemm_bt<1><<<ggrid, 256, 0, stream>>>(yb, wc2_, bc2 + (size_t)l*DDIM, nullptr, t0);
    ln_kernel<<<dim3(MROWS), dim3(64), 0, stream>>>(hf, t0, g2 + (size_t)l*DDIM, b2 + (size_t)l*DDIM, hf, hb);
  }
  ln_kernel<<<dim3(MROWS), dim3(64), 0, stream>>>(hf, nullptr, gf, bfin, t0, nullptr);
  final_kernel<<<dim3(BC), dim3(512), 0, stream>>>(t0, wsm, ph, out);
}

// Round 4
// 874.877 us; speedup vs baseline: 3.0147x; 1.4221x over previous
//
#include <hip/hip_runtime.h>
#include <hip/hip_bf16.h>

// ---------------- static problem config ----------------
#define BDIM 16
#define CDIM 32
#define LDIM 512
#define TDIM 65            // all_topk
#define DDIM 512
#define BC   (BDIM*CDIM)   // 512
#define MROWS (BC*TDIM)    // 33280
#define LN_EPS 1e-5f

typedef float fx4 __attribute__((ext_vector_type(4)));
typedef __bf16 bf16x8 __attribute__((ext_vector_type(8)));
typedef unsigned short us16;
typedef unsigned short us16x8 __attribute__((ext_vector_type(8)));

// ---------------- helpers ----------------
__device__ __forceinline__ us16 f2bf(float f){
  unsigned int u = __float_as_uint(f);
  u = (u + 0x7fffu + ((u >> 16) & 1u)) >> 16;
  return (us16)u;
}
__device__ __forceinline__ float bf2f(us16 s){
  return __uint_as_float(((unsigned int)s) << 16);
}
__device__ __forceinline__ float wred_max(float v){
  #pragma unroll
  for (int o = 32; o; o >>= 1) v = fmaxf(v, __shfl_xor(v, o));
  return v;
}
__device__ __forceinline__ float wred_sum(float v){
  #pragma unroll
  for (int o = 32; o; o >>= 1) v += __shfl_xor(v, o);
  return v;
}
__device__ __forceinline__ float gelu_exact(float x){
  return 0.5f * x * (1.0f + erff(x * 0.70710678118654752440f));
}
__device__ __forceinline__ void async16(void* lds, const void* g){
  __builtin_amdgcn_global_load_lds(
      (const __attribute__((address_space(1))) unsigned int*)g,
      (__attribute__((address_space(3))) unsigned int*)lds, 16, 0, 0);
}

// ---------------- K1: magnitude / phase ----------------
__global__ __launch_bounds__(256) void magph_kernel(
    const float* __restrict__ xr, const float* __restrict__ xi,
    float* __restrict__ mag, float* __restrict__ ph)
{
  int i = blockIdx.x * 256 + threadIdx.x;   // n = 262144 exact
  float r = xr[i], im = xi[i];
  mag[i] = sqrtf(r*r + im*im);
  ph[i]  = atan2f(im, r);
}

// ---------------- K2: per-frequency energy (double accum) ----------------
__global__ __launch_bounds__(64) void gm_kernel(
    const float* __restrict__ mag, double* __restrict__ gm)
{
  int l = blockIdx.x, t = threadIdx.x;
  double acc = 0.0;
  #pragma unroll
  for (int r = 0; r < 8; ++r){
    float v = mag[(size_t)(t + 64*r)*LDIM + l];
    acc += (double)v * (double)v;
  }
  #pragma unroll
  for (int o = 32; o; o >>= 1) acc += __shfl_xor(acc, o);
  if (t == 0) gm[l] = acc;
}

// ---------------- K3: top-k index selection ----------------
__device__ int wave_argmax(const float* val, int lo, int hi, int t){
  float bv = -3.4e38f; int bi = 0x7fffffff;
  for (int i = lo + t; i < hi; i += 64){
    float v = val[i];
    if (v > bv || (v == bv && i < bi)){ bv = v; bi = i; }
  }
  #pragma unroll
  for (int o = 32; o; o >>= 1){
    float ov = __shfl_xor(bv, o); int oi = __shfl_xor(bi, o);
    if (ov > bv || (ov == bv && oi < bi)){ bv = ov; bi = oi; }
  }
  return bi;
}

__global__ __launch_bounds__(64) void topk_kernel(
    const double* __restrict__ gm, int* __restrict__ idxo)
{
  __shared__ float val[LDIM];
  __shared__ float orig[LDIM];
  int t = threadIdx.x;
  for (int i = t; i < LDIM; i += 64){ float v = (float)gm[i]; val[i] = v; orig[i] = v; }
  __syncthreads();
  // global top-32 (argsort(-gm), stable ties -> smaller index)
  for (int s = 0; s < 32; ++s){
    int b = wave_argmax(val, 0, LDIM, t);
    if (t == 0){ idxo[s] = b; val[b] = -3.4e38f; }
    __syncthreads();
  }
  for (int i = t; i < LDIM; i += 64) val[i] = orig[i];
  __syncthreads();
  // 3 bands x top-11
  for (int bb = 0; bb < 3; ++bb){
    int s0 = bb*170, e0 = (bb == 2) ? LDIM : (bb+1)*170;
    for (int s = 0; s < 11; ++s){
      int b = wave_argmax(val, s0, e0, t);
      if (t == 0){ idxo[32 + bb*11 + s] = b; val[b] = -3.4e38f; }
      __syncthreads();
    }
  }
}

// ---------------- K4: gather key freqs + softmax weights ----------------
__global__ __launch_bounds__(64) void keygather_kernel(
    const float* __restrict__ mag, const float* __restrict__ ph, const int* __restrict__ idx,
    float* __restrict__ km, float* __restrict__ kp,
    float* __restrict__ kr, float* __restrict__ ki, float* __restrict__ wsm)
{
  int bc = blockIdx.x, t = threadIdx.x;
  int i0 = idx[t];
  int i1 = idx[64];
  float m0 = mag[(size_t)bc*LDIM + i0];
  float p0 = ph [(size_t)bc*LDIM + i0];
  float m1 = mag[(size_t)bc*LDIM + i1];
  float p1 = ph [(size_t)bc*LDIM + i1];
  size_t o = (size_t)bc*TDIM;
  km[o + t] = m0; kp[o + t] = p0;
  kr[o + t] = m0 * cosf(p0); ki[o + t] = m0 * sinf(p0);
  if (t == 0){
    km[o+64] = m1; kp[o+64] = p1;
    kr[o+64] = m1*cosf(p1); ki[o+64] = m1*sinf(p1);
  }
  // softmax over 65 key magnitudes
  float mx = wred_max(fmaxf(m0, m1));
  float e0 = expf(m0 - mx), e1 = expf(m1 - mx);
  float sum = wred_sum(e0) + e1;
  wsm[o + t] = e0 / sum;
  if (t == 0) wsm[o + 64] = e1 / sum;
}

// ---------------- K5: prob-distance + gumbel mask ----------------
__global__ __launch_bounds__(64) void distmask_kernel(
    const float* __restrict__ km, const float* __restrict__ kp,
    const float* __restrict__ A, const float* __restrict__ wAs, const float* __restrict__ wPs,
    const float* __restrict__ noise, float* __restrict__ mask)
{
  int b = blockIdx.x / TDIM, i = blockIdx.x % TDIM;
  int l = threadIdx.x;
  __shared__ float kmi[CDIM], kpi[CDIM];
  if (l < CDIM){
    kmi[l] = km[(size_t)(b*CDIM + l)*TDIM + i];
    kpi[l] = kp[(size_t)(b*CDIM + l)*TDIM + i];
  }
  __syncthreads();
  float wa = wAs[0], wp = wPs[0];
  float ed0, ed1 = 0.f;
  {
    int j = l;
    float Ad = A[j*TDIM + j];
    float acc = 0.f;
    for (int c = 0; c < CDIM; ++c){
      float d = Ad * (wa*(kmi[c] - km[(size_t)(b*CDIM+c)*TDIM + j])
                    + wp*(kpi[c] - kp[(size_t)(b*CDIM+c)*TDIM + j]));
      acc += d*d;
    }
    ed0 = (j == i) ? 0.f : 1.0f/(acc + 1e-10f);
  }
  if (l == 0){
    int j = 64;
    float Ad = A[j*TDIM + j];
    float acc = 0.f;
    for (int c = 0; c < CDIM; ++c){
      float d = Ad * (wa*(kmi[c] - km[(size_t)(b*CDIM+c)*TDIM + j])
                    + wp*(kpi[c] - kp[(size_t)(b*CDIM+c)*TDIM + j]));
      acc += d*d;
    }
    ed1 = (j == i) ? 0.f : 1.0f/(acc + 1e-10f);
  }
  float mx = ed0;
  if (l == 0) mx = fmaxf(mx, ed1);
  mx = wred_max(mx);
  // lane l -> j=l ; lane 0 also j=64
  {
    int j = l;
    float pv = (j == i) ? 0.99f : 0.99f * (ed0 / mx);
    float logit = logf(pv / (1.0f - pv));
    size_t n = ((size_t)b*TDIM + i)*TDIM + j;
    float g0 = noise[2*n], g1 = noise[2*n + 1];
    if (logit + g0 >= g1 - logit) atomicAdd(&mask[i*TDIM + j], 0.0625f);
  }
  if (l == 0){
    int j = 64;
    float pv = (j == i) ? 0.99f : 0.99f * (ed1 / mx);
    float logit = logf(pv / (1.0f - pv));
    size_t n = ((size_t)b*TDIM + i)*TDIM + j;
    float g0 = noise[2*n], g1 = noise[2*n + 1];
    if (logit + g0 >= g1 - logit) atomicAdd(&mask[i*TDIM + j], 0.0625f);
  }
}

// ---------------- K6: relationship tensor (complex sigmoid real part) ----------------
__global__ __launch_bounds__(256) void rel_kernel(
    const float* __restrict__ xr, const float* __restrict__ xi,
    const float* __restrict__ kr, const float* __restrict__ ki,
    us16* __restrict__ hb)
{
  size_t e = (size_t)blockIdx.x * 256 + threadIdx.x;  // 17,039,360 exact
  int d = (int)(e & 511);
  size_t mt = e >> 9;
  int t  = (int)(mt % TDIM);
  int bc = (int)(mt / TDIM);
  float krv = kr[(size_t)bc*TDIM + t], kiv = ki[(size_t)bc*TDIM + t];
  float r = xr[(size_t)bc*LDIM + d], im = xi[(size_t)bc*LDIM + d];
  float a  = krv*r - kiv*im;
  float bb = krv*im + kiv*r;
  float ea = expf(-a);
  float sn, cs; sincosf(bb, &sn, &cs);
  float wr = 1.0f + ea*cs;
  float wi = -ea*sn;
  float rel = wr / (wr*wr + wi*wi);
  hb[e] = f2bf(rel);
}

// ---------------- weight f32 -> bf16 ----------------
__global__ __launch_bounds__(256) void convert_kernel(
    const float* __restrict__ s, us16* __restrict__ d, int n)
{
  int i = blockIdx.x * 256 + threadIdx.x;
  if (i < n) d[i] = f2bf(s[i]);
}

// ---------------- GEMM: C[m,n] = sum_k X[m,k]*W[n,k] + bias[n] ----------------
// 128x128 tile, BK=32, 4 waves (2x2), mfma_f32_16x16x32_bf16.
// LDS: linear chunks, XOR slot-swizzle on both source addr and read addr (rule #21).
// EPI: 0 = store bf16 ; 2 = gelu -> bf16
template<int EPI>
__global__ __launch_bounds__(256) void gemm_bt(
    const us16* __restrict__ X, const us16* __restrict__ W,
    const float* __restrict__ bias, us16* __restrict__ outB)
{
  __shared__ us16 As[128*32];
  __shared__ us16 Bs[128*32];
  const int tid = threadIdx.x;
  const int w = tid >> 6, l = tid & 63;
  const int m0 = blockIdx.x * 128, n0 = blockIdx.y * 128;
  const int wm = w >> 1, wn = w & 1;
  const int g = l >> 4, li = l & 15;
  fx4 acc[4][4] = {};

  for (int k0 = 0; k0 < 512; k0 += 32){
    #pragma unroll
    for (int q = 0; q < 2; ++q){
      int c = w*128 + q*64 + l;
      int row = c >> 2, slot = c & 3;
      int koct = (slot ^ (row & 3)) << 3;
      const us16* srcA = X + (size_t)(m0 + row)*512 + k0 + koct;
      const us16* srcB = W + (size_t)(n0 + row)*512 + k0 + koct;
      async16(&As[(w*128 + q*64)*8], srcA);
      async16(&Bs[(w*128 + q*64)*8], srcB);
    }
    __syncthreads();
    bf16x8 aF[4], bF[4];
    #pragma unroll
    for (int mi = 0; mi < 4; ++mi){
      int r = wm*64 + mi*16 + li;
      int chunk = 4*r + (g ^ (r & 3));
      aF[mi] = *reinterpret_cast<const bf16x8*>(&As[chunk*8]);
    }
    #pragma unroll
    for (int ni = 0; ni < 4; ++ni){
      int cn = wn*64 + ni*16 + li;
      int chunk = 4*cn + (g ^ (cn & 3));
      bF[ni] = *reinterpret_cast<const bf16x8*>(&Bs[chunk*8]);
    }
    #pragma unroll
    for (int mi = 0; mi < 4; ++mi)
      #pragma unroll
      for (int ni = 0; ni < 4; ++ni)
        acc[mi][ni] = __builtin_amdgcn_mfma_f32_16x16x32_bf16(aF[mi], bF[ni], acc[mi][ni], 0, 0, 0);
    __syncthreads();
  }

  // epilogue — C/D layout: col = lane&15, row = (lane>>4)*4 + reg  [m89-verified]
  #pragma unroll
  for (int mi = 0; mi < 4; ++mi){
    #pragma unroll
    for (int ni = 0; ni < 4; ++ni){
      int col = n0 + wn*64 + ni*16 + li;
      float bv = bias[col];
      #pragma unroll
      for (int r = 0; r < 4; ++r){
        int row = m0 + wm*64 + mi*16 + g*4 + r;
        float v = acc[mi][ni][r] + bv;
        if (EPI == 2) v = gelu_exact(v);
        outB[(size_t)row*512 + col] = f2bf(v);
      }
    }
  }
}

// ---------------- attention v2: MFMA flash-style, one (bn,h) per 256-thr block ----
__global__ __launch_bounds__(256) void attn_mfma(
    const us16* __restrict__ qb, const us16* __restrict__ kb, const us16* __restrict__ vb,
    const float* __restrict__ mask, us16* __restrict__ ob)
{
  __shared__ __align__(16) us16 Qs[80*64];
  __shared__ __align__(16) us16 Ks[80*64];
  __shared__ __align__(16) us16 Vt[64*96];
  __shared__ __align__(16) us16 Pb[80*96];
  const int bn = blockIdx.x, h = blockIdx.y;
  const int tid = threadIdx.x;
  const int w = tid >> 6, l = tid & 63;
  const int g = l >> 4, li = l & 15;
  const size_t gbase = ((size_t)bn*TDIM)*512 + h*64;

  // ---- phase A: zero Vt/Pb, async-stage Q/K rows 0..63, reg-load V + row 64 ----
  {
    uint2 z = {0u, 0u};
    for (int u = tid; u < 1536; u += 256) ((uint2*)Vt)[u] = z;   // 12 KB
    for (int u = tid; u < 1920; u += 256) ((uint2*)Pb)[u] = z;   // 15 KB
  }
  #pragma unroll
  for (int it = 0; it < 2; ++it){
    int u = it*256 + tid;           // 0..511  -> rows 0..63, 8 slots each
    int r = u >> 3, ps = u & 7;
    int slog = ps ^ (r & 7);        // involution: phys slot ps holds logical octet slog
    async16(&Qs[(it*256 + w*64)*8], qb + gbase + (size_t)r*512 + slog*8);
    async16(&Ks[(it*256 + w*64)*8], kb + gbase + (size_t)r*512 + slog*8);
  }
  us16 vreg[17];
  #pragma unroll
  for (int i = 0; i < 17; ++i){
    int k = i*4 + w;
    if (k <= 64) vreg[i] = vb[gbase + (size_t)k*512 + l];
  }
  uint4 r64 = {};
  if (tid < 8)       r64 = *(const uint4*)(qb + gbase + (size_t)64*512 + tid*8);
  else if (tid < 16) r64 = *(const uint4*)(kb + gbase + (size_t)64*512 + (tid-8)*8);

  __syncthreads();   // drains vmcnt+lgkm: Q/K rows 0..63 staged, zeros done, regs ready

  // ---- phase C: Q/K row 64 + transposed V writes ----
  if (tid < 8)       *(uint4*)&Qs[(64*8 + tid)*8] = r64;     // row 64: r&7==0 -> linear
  else if (tid < 16) *(uint4*)&Ks[(64*8 + (tid-8))*8] = r64;
  #pragma unroll
  for (int i = 0; i < 17; ++i){
    int k = i*4 + w;
    if (k <= 64){
      int d = l, s = k >> 3;
      int ps = (s < 8) ? (s ^ (d & 7)) : (8 + ((s & 3) ^ (d & 3)));
      Vt[d*96 + ps*8 + (k & 7)] = vreg[i];
    }
  }
  __syncthreads();   // Vt + row64 visible to all waves

  // ---- per-wave M-tiles: wave w -> {w} (+{4} for wave 0). No barriers below. ----
  for (int m = w; m < 5; m += 4){
    const int mbase = m*16;
    // QK^T: S[i][j] = sum_k Q[i][k] K[j][k]
    fx4 acc[5] = {};
    #pragma unroll
    for (int kk = 0; kk < 2; ++kk){
      int ra = mbase + li;
      int sA = (kk*4 + g) ^ (ra & 7);
      bf16x8 aF = *(const bf16x8*)&Qs[ra*64 + sA*8];
      #pragma unroll
      for (int n = 0; n < 5; ++n){
        int rb = n*16 + li;
        int sB = (kk*4 + g) ^ (rb & 7);
        bf16x8 bF = *(const bf16x8*)&Ks[rb*64 + sB*8];
        acc[n] = __builtin_amdgcn_mfma_f32_16x16x32_bf16(aF, bF, acc[n], 0, 0, 0);
      }
    }
    // masked softmax; C layout: col = n*16+li, row = mbase + g*4 + reg
    float p[5][4];
    #pragma unroll
    for (int reg = 0; reg < 4; ++reg){
      int i = mbase + g*4 + reg;
      float sv[5], mx = -3.4e38f;
      #pragma unroll
      for (int n = 0; n < 5; ++n){
        int j = n*16 + li;
        if (j < TDIM){
          float mv = (i < TDIM) ? mask[i*TDIM + j] : 0.0f;
          sv[n] = (acc[n][reg]*mv + (1.0f - mv)*(-1e9f)) * 0.125f;
        } else sv[n] = -3.4e38f;              // excluded; never touches garbage scores
        mx = fmaxf(mx, sv[n]);
      }
      #pragma unroll
      for (int o = 1; o < 16; o <<= 1) mx = fmaxf(mx, __shfl_xor(mx, o));
      float sum = 0.f;
      #pragma unroll
      for (int n = 0; n < 5; ++n){
        int j = n*16 + li;
        float e = (j < TDIM) ? expf(sv[n] - mx) : 0.0f;
        p[n][reg] = e; sum += e;
      }
      #pragma unroll
      for (int o = 1; o < 16; o <<= 1) sum += __shfl_xor(sum, o);
      float inv = 1.0f / sum;
      #pragma unroll
      for (int n = 0; n < 5; ++n) p[n][reg] *= inv;
    }
    // write P -> Pb bf16 (own rows only; within-wave producer/consumer)
    #pragma unroll
    for (int n = 0; n < 5; ++n){
      int j = n*16 + li, s = j >> 3, jo = j & 7;
      #pragma unroll
      for (int reg = 0; reg < 4; ++reg){
        int r = mbase + g*4 + reg;
        int ps = (s < 8) ? (s ^ (r & 7)) : (8 + ((s & 3) ^ (r & 3)));
        Pb[r*96 + ps*8 + jo] = f2bf(p[n][reg]);
      }
    }
    asm volatile("s_waitcnt lgkmcnt(0)" ::: "memory");  // P writes landed before reads
    // PV: O[i][d] = sum_j P[i][j] V[j][d]  (A=P from Pb, B=V^T from Vt)
    fx4 acc2[4] = {};
    #pragma unroll
    for (int kk = 0; kk < 3; ++kk){
      int ra = mbase + li;
      int s = kk*4 + g;
      int psA = (s < 8) ? (s ^ (ra & 7)) : (8 + ((s & 3) ^ (ra & 3)));
      bf16x8 pF = *(const bf16x8*)&Pb[ra*96 + psA*8];
      #pragma unroll
      for (int n2 = 0; n2 < 4; ++n2){
        int d = n2*16 + li;
        int psB = (s < 8) ? (s ^ (d & 7)) : (8 + ((s & 3) ^ (d & 3)));
        bf16x8 vF = *(const bf16x8*)&Vt[d*96 + psB*8];
        acc2[n2] = __builtin_amdgcn_mfma_f32_16x16x32_bf16(pF, vF, acc2[n2], 0, 0, 0);
      }
    }
    // store O rows < 65
    #pragma unroll
    for (int n2 = 0; n2 < 4; ++n2){
      int d = n2*16 + li;
      #pragma unroll
      for (int reg = 0; reg < 4; ++reg){
        int i = mbase + g*4 + reg;
        if (i < TDIM) ob[gbase + (size_t)i*512 + d] = f2bf(acc2[n2][reg]);
      }
    }
  }
}

// ---------------- layernorm bf16 (+ optional bf16 residual), 4 rows/block ----------
__global__ __launch_bounds__(256) void ln_kernel(
    const us16* __restrict__ X, const us16* __restrict__ R,
    const float* __restrict__ g, const float* __restrict__ b,
    us16* __restrict__ out)
{
  int row = blockIdx.x*4 + (threadIdx.x >> 6);
  int l = threadIdx.x & 63;
  size_t base = (size_t)row*DDIM + l*8;
  us16x8 xv = *(const us16x8*)(X + base);
  float v[8];
  #pragma unroll
  for (int e = 0; e < 8; ++e) v[e] = bf2f(xv[e]);
  if (R){
    us16x8 rv = *(const us16x8*)(R + base);
    #pragma unroll
    for (int e = 0; e < 8; ++e) v[e] += bf2f(rv[e]);
  }
  float s = 0.f;
  #pragma unroll
  for (int e = 0; e < 8; ++e) s += v[e];
  float mu = wred_sum(s) * (1.0f/512.0f);
  float qq = 0.f;
  #pragma unroll
  for (int e = 0; e < 8; ++e){ float d = v[e] - mu; qq += d*d; }
  float var = wred_sum(qq) * (1.0f/512.0f);
  float inv = 1.0f / sqrtf(var + LN_EPS);
  fx4 g0 = *(const fx4*)&g[l*8], g1 = *(const fx4*)&g[l*8 + 4];
  fx4 b0 = *(const fx4*)&b[l*8], b1 = *(const fx4*)&b[l*8 + 4];
  us16x8 o;
  #pragma unroll
  for (int e = 0; e < 4; ++e){
    o[e]     = f2bf((v[e]   - mu) * inv * g0[e] + b0[e]);
    o[e + 4] = f2bf((v[e+4] - mu) * inv * g1[e] + b1[e]);
  }
  *(us16x8*)(out + base) = o;
}

// ---------------- final weighted sum + polar ----------------
__global__ __launch_bounds__(512) void final_kernel(
    const us16* __restrict__ hfin, const float* __restrict__ wsm,
    const float* __restrict__ ph, float* __restrict__ out)
{
  int bc = blockIdx.x, d = threadIdx.x;
  __shared__ float wv[TDIM];
  if (d < TDIM) wv[d] = wsm[(size_t)bc*TDIM + d];
  __syncthreads();
  float fs = 0.f;
  for (int t = 0; t < TDIM; ++t)
    fs += bf2f(hfin[((size_t)bc*TDIM + t)*DDIM + d]) * wv[t];
  float p = ph[(size_t)bc*LDIM + d];
  float sn, cs; sincosf(p, &sn, &cs);
  out[((size_t)bc*LDIM + d)*2 + 0] = fs * cs;
  out[((size_t)bc*LDIM + d)*2 + 1] = fs * sn;
}

// ---------------- launch ----------------
extern "C" void kernel_launch(void* const* d_in, const int* in_sizes, int n_in,
                              void* d_out, int out_size, void* d_ws, size_t ws_size,
                              hipStream_t stream)
{
  const float* xr    = (const float*)d_in[0];
  const float* xi    = (const float*)d_in[1];
  const float* noise = (const float*)d_in[2];
  const float* Amat  = (const float*)d_in[3];
  const float* wA    = (const float*)d_in[4];
  const float* wP    = (const float*)d_in[5];
  const float* Wq    = (const float*)d_in[6];
  const float* bq    = (const float*)d_in[7];
  const float* Wk    = (const float*)d_in[8];
  const float* bk    = (const float*)d_in[9];
  const float* Wv    = (const float*)d_in[10];
  const float* bv    = (const float*)d_in[11];
  const float* Wo    = (const float*)d_in[12];
  const float* bo    = (const float*)d_in[13];
  const float* Wc1   = (const float*)d_in[14];
  const float* bc1   = (const float*)d_in[15];
  const float* Wc2   = (const float*)d_in[16];
  const float* bc2   = (const float*)d_in[17];
  const float* g1    = (const float*)d_in[18];
  const float* b1    = (const float*)d_in[19];
  const float* g2    = (const float*)d_in[20];
  const float* b2    = (const float*)d_in[21];
  const float* gf    = (const float*)d_in[22];
  const float* bfin  = (const float*)d_in[23];
  float* out = (float*)d_out;

  char* p = (char*)d_ws;
  auto take = [&](size_t bytes) -> char* {
    char* r = p; p += (bytes + 255) & ~(size_t)255; return r;
  };
  float*  mag  = (float*)take((size_t)BC*LDIM*4);
  float*  ph   = (float*)take((size_t)BC*LDIM*4);
  double* gm   = (double*)take(LDIM*8);
  int*    idx  = (int*)take(TDIM*4);
  float*  km   = (float*)take((size_t)BC*TDIM*4);
  float*  kp   = (float*)take((size_t)BC*TDIM*4);
  float*  kr   = (float*)take((size_t)BC*TDIM*4);
  float*  ki   = (float*)take((size_t)BC*TDIM*4);
  float*  wsm  = (float*)take((size_t)BC*TDIM*4);
  float*  mask = (float*)take(TDIM*TDIM*4);
  us16*   wbf  = (us16*)take((size_t)6*2*DDIM*DDIM*2);
  us16*   hb   = (us16*)take((size_t)MROWS*DDIM*2);   // bf16 residual stream
  us16*   qb   = (us16*)take((size_t)MROWS*DDIM*2);
  us16*   kb2  = (us16*)take((size_t)MROWS*DDIM*2);
  us16*   vb2  = (us16*)take((size_t)MROWS*DDIM*2);
  us16*   ob   = (us16*)take((size_t)MROWS*DDIM*2);
  us16*   t0b  = vb2;   // alias — vb2 dead once attn (its only reader) completes
  us16*   yb   = qb;    // alias — qb dead once attn completes

  magph_kernel<<<dim3(1024), dim3(256), 0, stream>>>(xr, xi, mag, ph);
  gm_kernel<<<dim3(LDIM), dim3(64), 0, stream>>>(mag, gm);
  topk_kernel<<<dim3(1), dim3(64), 0, stream>>>(gm, idx);
  keygather_kernel<<<dim3(BC), dim3(64), 0, stream>>>(mag, ph, idx, km, kp, kr, ki, wsm);
  hipMemsetAsync(mask, 0, TDIM*TDIM*4, stream);
  distmask_kernel<<<dim3(BDIM*TDIM), dim3(64), 0, stream>>>(km, kp, Amat, wA, wP, noise, mask);
  rel_kernel<<<dim3(66560), dim3(256), 0, stream>>>(xr, xi, kr, ki, hb);

  const float* Wsrc[6] = {Wq, Wk, Wv, Wo, Wc1, Wc2};
  for (int m = 0; m < 6; ++m)
    convert_kernel<<<dim3(2048), dim3(256), 0, stream>>>(
        Wsrc[m], wbf + (size_t)m*2*DDIM*DDIM, 2*DDIM*DDIM);

  dim3 ggrid(MROWS/128, DDIM/128);
  for (int l = 0; l < 2; ++l){
    const us16* wq_  = wbf + ((size_t)0*2 + l)*DDIM*DDIM;
    const us16* wk_  = wbf + ((size_t)1*2 + l)*DDIM*DDIM;
    const us16* wv_  = wbf + ((size_t)2*2 + l)*DDIM*DDIM;
    const us16* wo_  = wbf + ((size_t)3*2 + l)*DDIM*DDIM;
    const us16* wc1_ = wbf + ((size_t)4*2 + l)*DDIM*DDIM;
    const us16* wc2_ = wbf + ((size_t)5*2 + l)*DDIM*DDIM;

    gemm_bt<0><<<ggrid, 256, 0, stream>>>(hb, wq_, bq + (size_t)l*DDIM, qb);
    gemm_bt<0><<<ggrid, 256, 0, stream>>>(hb, wk_, bk + (size_t)l*DDIM, kb2);
    gemm_bt<0><<<ggrid, 256, 0, stream>>>(hb, wv_, bv + (size_t)l*DDIM, vb2);
    attn_mfma<<<dim3(BC, 8), dim3(256), 0, stream>>>(qb, kb2, vb2, mask, ob);
    gemm_bt<0><<<ggrid, 256, 0, stream>>>(ob, wo_, bo + (size_t)l*DDIM, t0b);
    ln_kernel<<<dim3(MROWS/4), dim3(256), 0, stream>>>(t0b, hb, g1 + (size_t)l*DDIM, b1 + (size_t)l*DDIM, hb);
    gemm_bt<2><<<ggrid, 256, 0, stream>>>(hb, wc1_, bc1 + (size_t)l*DDIM, yb);
    gemm_bt<0><<<ggrid, 256, 0, stream>>>(yb, wc2_, bc2 + (size_t)l*DDIM, t0b);
    ln_kernel<<<dim3(MROWS/4), dim3(256), 0, stream>>>(t0b, hb, g2 + (size_t)l*DDIM, b2 + (size_t)l*DDIM, hb);
  }
  ln_kernel<<<dim3(MROWS/4), dim3(256), 0, stream>>>(hb, nullptr, gf, bfin, t0b);
  final_kernel<<<dim3(BC), dim3(512), 0, stream>>>(t0b, wsm, ph, out);
}

// Round 5
// 821.171 us; speedup vs baseline: 3.2119x; 1.0654x over previous
//
#include <hip/hip_runtime.h>
#include <hip/hip_bf16.h>

// ---------------- static problem config ----------------
#define BDIM 16
#define CDIM 32
#define LDIM 512
#define TDIM 65            // all_topk
#define DDIM 512
#define BC   (BDIM*CDIM)   // 512
#define MROWS (BC*TDIM)    // 33280
#define LN_EPS 1e-5f

typedef float fx4 __attribute__((ext_vector_type(4)));
typedef __bf16 bf16x8 __attribute__((ext_vector_type(8)));
typedef unsigned short us16;
typedef unsigned short us16x8 __attribute__((ext_vector_type(8)));

// ---------------- helpers ----------------
__device__ __forceinline__ us16 f2bf(float f){
  unsigned int u = __float_as_uint(f);
  u = (u + 0x7fffu + ((u >> 16) & 1u)) >> 16;
  return (us16)u;
}
__device__ __forceinline__ float bf2f(us16 s){
  return __uint_as_float(((unsigned int)s) << 16);
}
__device__ __forceinline__ float wred_max(float v){
  #pragma unroll
  for (int o = 32; o; o >>= 1) v = fmaxf(v, __shfl_xor(v, o));
  return v;
}
__device__ __forceinline__ float wred_sum(float v){
  #pragma unroll
  for (int o = 32; o; o >>= 1) v += __shfl_xor(v, o);
  return v;
}
__device__ __forceinline__ float gelu_exact(float x){
  return 0.5f * x * (1.0f + erff(x * 0.70710678118654752440f));
}
__device__ __forceinline__ void async16(void* lds, const void* g){
  __builtin_amdgcn_global_load_lds(
      (const __attribute__((address_space(1))) unsigned int*)g,
      (__attribute__((address_space(3))) unsigned int*)lds, 16, 0, 0);
}

// ---------------- K1: magnitude / phase ----------------
__global__ __launch_bounds__(256) void magph_kernel(
    const float* __restrict__ xr, const float* __restrict__ xi,
    float* __restrict__ mag, float* __restrict__ ph)
{
  int i = blockIdx.x * 256 + threadIdx.x;   // n = 262144 exact
  float r = xr[i], im = xi[i];
  mag[i] = sqrtf(r*r + im*im);
  ph[i]  = atan2f(im, r);
}

// ---------------- K2: per-frequency energy (double accum) ----------------
__global__ __launch_bounds__(64) void gm_kernel(
    const float* __restrict__ mag, double* __restrict__ gm)
{
  int l = blockIdx.x, t = threadIdx.x;
  double acc = 0.0;
  #pragma unroll
  for (int r = 0; r < 8; ++r){
    float v = mag[(size_t)(t + 64*r)*LDIM + l];
    acc += (double)v * (double)v;
  }
  #pragma unroll
  for (int o = 32; o; o >>= 1) acc += __shfl_xor(acc, o);
  if (t == 0) gm[l] = acc;
}

// ---------------- K3: parallel rank-select top-k ----------------
// rank_i = #{o : gm[o] > gm[i] or (gm[o]==gm[i] and o<i)}  == stable argsort(-gm) position.
__global__ __launch_bounds__(256) void topk_kernel(
    const double* __restrict__ gm, int* __restrict__ idxo)
{
  __shared__ float val[LDIM];
  int t = threadIdx.x;
  int i = blockIdx.x * 256 + t;
  val[t] = (float)gm[t];
  val[t + 256] = (float)gm[t + 256];
  __syncthreads();
  float vi = val[i];
  int band = (i < 170) ? 0 : (i < 340 ? 1 : 2);
  int lo = band * 170;
  int hi = (band == 2) ? LDIM : lo + 170;
  int gr = 0, br = 0;
  #pragma unroll 4
  for (int o = 0; o < LDIM; ++o){
    float vo = val[o];
    bool ahead = (vo > vi) || (vo == vi && o < i);
    gr += ahead ? 1 : 0;
    br += (ahead && o >= lo && o < hi) ? 1 : 0;
  }
  if (gr < 32) idxo[gr] = i;
  if (br < 11) idxo[32 + band*11 + br] = i;
}

// ---------------- K4: gather key freqs + softmax weights ----------------
__global__ __launch_bounds__(64) void keygather_kernel(
    const float* __restrict__ mag, const float* __restrict__ ph, const int* __restrict__ idx,
    float* __restrict__ km, float* __restrict__ kp,
    float* __restrict__ kr, float* __restrict__ ki, float* __restrict__ wsm)
{
  int bc = blockIdx.x, t = threadIdx.x;
  int i0 = idx[t];
  int i1 = idx[64];
  float m0 = mag[(size_t)bc*LDIM + i0];
  float p0 = ph [(size_t)bc*LDIM + i0];
  float m1 = mag[(size_t)bc*LDIM + i1];
  float p1 = ph [(size_t)bc*LDIM + i1];
  size_t o = (size_t)bc*TDIM;
  km[o + t] = m0; kp[o + t] = p0;
  kr[o + t] = m0 * cosf(p0); ki[o + t] = m0 * sinf(p0);
  if (t == 0){
    km[o+64] = m1; kp[o+64] = p1;
    kr[o+64] = m1*cosf(p1); ki[o+64] = m1*sinf(p1);
  }
  // softmax over 65 key magnitudes
  float mx = wred_max(fmaxf(m0, m1));
  float e0 = expf(m0 - mx), e1 = expf(m1 - mx);
  float sum = wred_sum(e0) + e1;
  wsm[o + t] = e0 / sum;
  if (t == 0) wsm[o + 64] = e1 / sum;
}

// ---------------- K5: prob-distance + gumbel mask ----------------
__global__ __launch_bounds__(64) void distmask_kernel(
    const float* __restrict__ km, const float* __restrict__ kp,
    const float* __restrict__ A, const float* __restrict__ wAs, const float* __restrict__ wPs,
    const float* __restrict__ noise, float* __restrict__ mask)
{
  int b = blockIdx.x / TDIM, i = blockIdx.x % TDIM;
  int l = threadIdx.x;
  __shared__ float kmi[CDIM], kpi[CDIM];
  if (l < CDIM){
    kmi[l] = km[(size_t)(b*CDIM + l)*TDIM + i];
    kpi[l] = kp[(size_t)(b*CDIM + l)*TDIM + i];
  }
  __syncthreads();
  float wa = wAs[0], wp = wPs[0];
  float ed0, ed1 = 0.f;
  {
    int j = l;
    float Ad = A[j*TDIM + j];
    float acc = 0.f;
    for (int c = 0; c < CDIM; ++c){
      float d = Ad * (wa*(kmi[c] - km[(size_t)(b*CDIM+c)*TDIM + j])
                    + wp*(kpi[c] - kp[(size_t)(b*CDIM+c)*TDIM + j]));
      acc += d*d;
    }
    ed0 = (j == i) ? 0.f : 1.0f/(acc + 1e-10f);
  }
  if (l == 0){
    int j = 64;
    float Ad = A[j*TDIM + j];
    float acc = 0.f;
    for (int c = 0; c < CDIM; ++c){
      float d = Ad * (wa*(kmi[c] - km[(size_t)(b*CDIM+c)*TDIM + j])
                    + wp*(kpi[c] - kp[(size_t)(b*CDIM+c)*TDIM + j]));
      acc += d*d;
    }
    ed1 = (j == i) ? 0.f : 1.0f/(acc + 1e-10f);
  }
  float mx = ed0;
  if (l == 0) mx = fmaxf(mx, ed1);
  mx = wred_max(mx);
  {
    int j = l;
    float pv = (j == i) ? 0.99f : 0.99f * (ed0 / mx);
    float logit = logf(pv / (1.0f - pv));
    size_t n = ((size_t)b*TDIM + i)*TDIM + j;
    float g0 = noise[2*n], g1 = noise[2*n + 1];
    if (logit + g0 >= g1 - logit) atomicAdd(&mask[i*TDIM + j], 0.0625f);
  }
  if (l == 0){
    int j = 64;
    float pv = (j == i) ? 0.99f : 0.99f * (ed1 / mx);
    float logit = logf(pv / (1.0f - pv));
    size_t n = ((size_t)b*TDIM + i)*TDIM + j;
    float g0 = noise[2*n], g1 = noise[2*n + 1];
    if (logit + g0 >= g1 - logit) atomicAdd(&mask[i*TDIM + j], 0.0625f);
  }
}

// ---------------- K6: relationship tensor (complex sigmoid real part) ----------------
__global__ __launch_bounds__(256) void rel_kernel(
    const float* __restrict__ xr, const float* __restrict__ xi,
    const float* __restrict__ kr, const float* __restrict__ ki,
    us16* __restrict__ hb)
{
  size_t e = (size_t)blockIdx.x * 256 + threadIdx.x;  // 17,039,360 exact
  int d = (int)(e & 511);
  size_t mt = e >> 9;
  int t  = (int)(mt % TDIM);
  int bc = (int)(mt / TDIM);
  float krv = kr[(size_t)bc*TDIM + t], kiv = ki[(size_t)bc*TDIM + t];
  float r = xr[(size_t)bc*LDIM + d], im = xi[(size_t)bc*LDIM + d];
  float a  = krv*r - kiv*im;
  float bb = krv*im + kiv*r;
  float ea = expf(-a);
  float sn, cs; sincosf(bb, &sn, &cs);
  float wr = 1.0f + ea*cs;
  float wi = -ea*sn;
  float rel = wr / (wr*wr + wi*wi);
  hb[e] = f2bf(rel);
}

// ---------------- fused weight convert + QKV concat + bias concat ----------------
struct WPtrs { const float* s[6]; };
__global__ __launch_bounds__(256) void convert_all(
    WPtrs wp, const float* __restrict__ bq, const float* __restrict__ bk,
    const float* __restrict__ bv,
    us16* __restrict__ wqkv, us16* __restrict__ wo,
    us16* __restrict__ wc1, us16* __restrict__ wc2, float* __restrict__ bqkv)
{
  size_t i = (size_t)blockIdx.x * 256 + threadIdx.x;   // 3,145,728 exact
  int m   = (int)(i >> 19);        // matrix 0..5
  int rem = (int)(i & 524287);     // [2][512][512] flat
  int l   = rem >> 18;
  us16 b = f2bf(wp.s[m][rem]);
  if (m < 3)      wqkv[(size_t)l*786432 + m*262144 + (rem & 262143)] = b;
  else if (m == 3) wo[rem]  = b;
  else if (m == 4) wc1[rem] = b;
  else             wc2[rem] = b;
  if (i < 3072){
    int l2 = (int)(i >> 11);       // 0 or 1 (1536 per layer)
    int n  = (int)(i & 1535);
    int mm = n >> 9, c = n & 511;
    const float* bs = (mm == 0) ? bq : ((mm == 1) ? bk : bv);
    bqkv[i] = bs[l2*512 + c];
  }
}

// ---------------- GEMM: C[m,n] = sum_k X[m,k]*W[n,k] + bias[n] ----------------
// 128x128 tile, BK=64, 4 waves (2x2), mfma_f32_16x16x32_bf16, 32 KB LDS.
// LDS rows of 8 16B-slots, slot XOR-swizzled by (row&7) on both the
// global-source side and the read side (rule #21).
// Output routed to one of 3 buffers by fused-N block (for QKV fusion).
// EPI: 0 = store bf16 ; 2 = gelu -> bf16
template<int EPI>
__global__ __launch_bounds__(256) void gemm_bt(
    const us16* __restrict__ X, const us16* __restrict__ W,
    const float* __restrict__ bias,
    us16* __restrict__ o0, us16* __restrict__ o1, us16* __restrict__ o2)
{
  __shared__ us16 As[128*64];
  __shared__ us16 Bs[128*64];
  const int tid = threadIdx.x;
  const int w = tid >> 6, l = tid & 63;
  const int m0 = blockIdx.x * 128, n0 = blockIdx.y * 128;
  const int wm = w >> 1, wn = w & 1;
  const int g = l >> 4, li = l & 15;
  fx4 acc[4][4] = {};

  for (int k0 = 0; k0 < 512; k0 += 64){
    #pragma unroll
    for (int q = 0; q < 4; ++q){
      int c = q*256 + tid;          // 0..1023 ; per wave contiguous in lane
      int row = c >> 3, ps = c & 7;
      int sl = ps ^ (row & 7);      // involution
      async16(&As[c*8], X + (size_t)(m0 + row)*512 + k0 + sl*8);
      async16(&Bs[c*8], W + (size_t)(n0 + row)*512 + k0 + sl*8);
    }
    __syncthreads();
    #pragma unroll
    for (int kk = 0; kk < 2; ++kk){
      bf16x8 aF[4], bF[4];
      #pragma unroll
      for (int mi = 0; mi < 4; ++mi){
        int r = wm*64 + mi*16 + li;
        int s = (kk*4 + g) ^ (r & 7);
        aF[mi] = *reinterpret_cast<const bf16x8*>(&As[(r*8 + s)*8]);
      }
      #pragma unroll
      for (int ni = 0; ni < 4; ++ni){
        int rn = wn*64 + ni*16 + li;
        int s = (kk*4 + g) ^ (rn & 7);
        bF[ni] = *reinterpret_cast<const bf16x8*>(&Bs[(rn*8 + s)*8]);
      }
      #pragma unroll
      for (int mi = 0; mi < 4; ++mi)
        #pragma unroll
        for (int ni = 0; ni < 4; ++ni)
          acc[mi][ni] = __builtin_amdgcn_mfma_f32_16x16x32_bf16(aF[mi], bF[ni], acc[mi][ni], 0, 0, 0);
    }
    __syncthreads();
  }

  // epilogue — C/D layout: col = lane&15, row = (lane>>4)*4 + reg  [m89-verified]
  const int sel = n0 >> 9;                 // block-uniform (128 | 512)
  us16* dst = (sel == 0) ? o0 : ((sel == 1) ? o1 : o2);
  #pragma unroll
  for (int mi = 0; mi < 4; ++mi){
    #pragma unroll
    for (int ni = 0; ni < 4; ++ni){
      int coln = wn*64 + ni*16 + li;
      float bv = bias[n0 + coln];
      int col = (n0 & 511) + coln;
      #pragma unroll
      for (int r = 0; r < 4; ++r){
        int row = m0 + wm*64 + mi*16 + g*4 + r;
        float v = acc[mi][ni][r] + bv;
        if (EPI == 2) v = gelu_exact(v);
        dst[(size_t)row*512 + col] = f2bf(v);
      }
    }
  }
}

// ---------------- attention: MFMA flash-style, one (bn,h) per 256-thr block ----
// Qs/Ks: [80][64] bf16, 8 slots/row XOR-swizzled by (row&7). Vt: V^T [64][96],
// slots<8 swizzled, slots>=8 identity; k in [65,96) zeroed (NaN x 0 guard).
// Pb: P bf16 [80][96], slots<8 swizzled, slots 8..9 written (incl. zeros for
// j in [65,80)), slots 10..11 zeroed.
__global__ __launch_bounds__(256) void attn_mfma(
    const us16* __restrict__ qb, const us16* __restrict__ kb, const us16* __restrict__ vb,
    const float* __restrict__ mask, us16* __restrict__ ob)
{
  __shared__ __align__(16) us16 Qs[80*64];
  __shared__ __align__(16) us16 Ks[80*64];
  __shared__ __align__(16) us16 Vt[64*96];
  __shared__ __align__(16) us16 Pb[80*96];
  const int bn = blockIdx.x, h = blockIdx.y;
  const int tid = threadIdx.x;
  const int w = tid >> 6, l = tid & 63;
  const int g = l >> 4, li = l & 15;
  const size_t gbase = ((size_t)bn*TDIM)*512 + h*64;

  // ---- phase A: zero tails, async-stage Q/K rows 0..63, reg-load V + row 64 ----
  {
    uint4 z = {0u,0u,0u,0u};
    if (tid < 160){ int r = tid >> 1, sl = 10 + (tid & 1); *(uint4*)&Pb[r*96 + sl*8] = z; }
    if (tid < 192){ int r = tid & 63, sl = 9 + (tid >> 6); *(uint4*)&Vt[r*96 + sl*8] = z; }
  }
  #pragma unroll
  for (int it = 0; it < 2; ++it){
    int u = it*256 + tid;           // 0..511  -> rows 0..63, 8 slots each
    int r = u >> 3, ps = u & 7;
    int slog = ps ^ (r & 7);
    async16(&Qs[(it*256 + w*64)*8], qb + gbase + (size_t)r*512 + slog*8);
    async16(&Ks[(it*256 + w*64)*8], kb + gbase + (size_t)r*512 + slog*8);
  }
  us16 vreg[16];
  #pragma unroll
  for (int j = 0; j < 16; ++j)
    vreg[j] = vb[gbase + (size_t)(w*16 + j)*512 + l];
  us16 v64v = 0;
  if (tid < 64) v64v = vb[gbase + (size_t)64*512 + tid];
  uint4 r64 = {};
  if (tid < 8)       r64 = *(const uint4*)(qb + gbase + (size_t)64*512 + tid*8);
  else if (tid < 16) r64 = *(const uint4*)(kb + gbase + (size_t)64*512 + (tid-8)*8);

  __syncthreads();   // Q/K rows staged, zeros done, regs ready

  // ---- phase C: Q/K row 64 + transposed V writes (2 x b128 per thread) ----
  if (tid < 8)       *(uint4*)&Qs[(64*8 + tid)*8] = r64;     // row 64: r&7==0 -> linear
  else if (tid < 16) *(uint4*)&Ks[(64*8 + (tid-8))*8] = r64;
  {
    us16x8 lo, hi;
    #pragma unroll
    for (int j = 0; j < 8; ++j){ lo[j] = vreg[j]; hi[j] = vreg[8+j]; }
    int s0 = w*2, s1 = w*2 + 1;
    *(us16x8*)&Vt[l*96 + (s0 ^ (l & 7))*8] = lo;
    *(us16x8*)&Vt[l*96 + (s1 ^ (l & 7))*8] = hi;
  }
  if (tid < 64){
    us16x8 t8 = {};
    t8[0] = v64v;
    *(us16x8*)&Vt[tid*96 + 8*8] = t8;      // slot 8 identity; k=65..71 zeroed
  }
  __syncthreads();   // Vt + row64 visible

  // ---- per-wave M-tiles: wave w -> {w} (+{4} for wave 0). No barriers below. ----
  for (int m = w; m < 5; m += 4){
    const int mbase = m*16;
    // QK^T
    fx4 acc[5] = {};
    #pragma unroll
    for (int kk = 0; kk < 2; ++kk){
      int ra = mbase + li;
      int sA = (kk*4 + g) ^ (ra & 7);
      bf16x8 aF = *(const bf16x8*)&Qs[ra*64 + sA*8];
      #pragma unroll
      for (int n = 0; n < 5; ++n){
        int rb = n*16 + li;
        int sB = (kk*4 + g) ^ (rb & 7);
        bf16x8 bF = *(const bf16x8*)&Ks[rb*64 + sB*8];
        acc[n] = __builtin_amdgcn_mfma_f32_16x16x32_bf16(aF, bF, acc[n], 0, 0, 0);
      }
    }
    // masked softmax; C layout: col = n*16+li, row = mbase + g*4 + reg
    float p[5][4];
    #pragma unroll
    for (int reg = 0; reg < 4; ++reg){
      int i = mbase + g*4 + reg;
      float sv[5], mx = -3.4e38f;
      #pragma unroll
      for (int n = 0; n < 5; ++n){
        int j = n*16 + li;
        if (j < TDIM){
          float mv = (i < TDIM) ? mask[i*TDIM + j] : 0.0f;
          sv[n] = (acc[n][reg]*mv + (1.0f - mv)*(-1e9f)) * 0.125f;
        } else sv[n] = -3.4e38f;
        mx = fmaxf(mx, sv[n]);
      }
      #pragma unroll
      for (int o = 1; o < 16; o <<= 1) mx = fmaxf(mx, __shfl_xor(mx, o));
      float sum = 0.f;
      #pragma unroll
      for (int n = 0; n < 5; ++n){
        int j = n*16 + li;
        float e = (j < TDIM) ? expf(sv[n] - mx) : 0.0f;
        p[n][reg] = e; sum += e;
      }
      #pragma unroll
      for (int o = 1; o < 16; o <<= 1) sum += __shfl_xor(sum, o);
      float inv = 1.0f / sum;
      #pragma unroll
      for (int n = 0; n < 5; ++n) p[n][reg] *= inv;
    }
    // write P -> Pb (own rows only; within-wave producer/consumer)
    #pragma unroll
    for (int n = 0; n < 5; ++n){
      int j = n*16 + li, s = j >> 3, jo = j & 7;
      #pragma unroll
      for (int reg = 0; reg < 4; ++reg){
        int r = mbase + g*4 + reg;
        int ps = (s < 8) ? (s ^ (r & 7)) : s;
        Pb[r*96 + ps*8 + jo] = f2bf(p[n][reg]);
      }
    }
    asm volatile("s_waitcnt lgkmcnt(0)" ::: "memory");
    // PV: O[i][d] = sum_j P[i][j] V[j][d]
    fx4 acc2[4] = {};
    #pragma unroll
    for (int kk = 0; kk < 3; ++kk){
      int ra = mbase + li;
      int s = kk*4 + g;
      int psA = (s < 8) ? (s ^ (ra & 7)) : s;
      bf16x8 pF = *(const bf16x8*)&Pb[ra*96 + psA*8];
      #pragma unroll
      for (int n2 = 0; n2 < 4; ++n2){
        int d = n2*16 + li;
        int psB = (s < 8) ? (s ^ (d & 7)) : s;
        bf16x8 vF = *(const bf16x8*)&Vt[d*96 + psB*8];
        acc2[n2] = __builtin_amdgcn_mfma_f32_16x16x32_bf16(pF, vF, acc2[n2], 0, 0, 0);
      }
    }
    #pragma unroll
    for (int n2 = 0; n2 < 4; ++n2){
      int d = n2*16 + li;
      #pragma unroll
      for (int reg = 0; reg < 4; ++reg){
        int i = mbase + g*4 + reg;
        if (i < TDIM) ob[gbase + (size_t)i*512 + d] = f2bf(acc2[n2][reg]);
      }
    }
  }
}

// ---------------- layernorm bf16 (+ optional bf16 residual), 4 rows/block ----------
__global__ __launch_bounds__(256) void ln_kernel(
    const us16* __restrict__ X, const us16* __restrict__ R,
    const float* __restrict__ g, const float* __restrict__ b,
    us16* __restrict__ out)
{
  int row = blockIdx.x*4 + (threadIdx.x >> 6);
  int l = threadIdx.x & 63;
  size_t base = (size_t)row*DDIM + l*8;
  us16x8 xv = *(const us16x8*)(X + base);
  float v[8];
  #pragma unroll
  for (int e = 0; e < 8; ++e) v[e] = bf2f(xv[e]);
  if (R){
    us16x8 rv = *(const us16x8*)(R + base);
    #pragma unroll
    for (int e = 0; e < 8; ++e) v[e] += bf2f(rv[e]);
  }
  float s = 0.f;
  #pragma unroll
  for (int e = 0; e < 8; ++e) s += v[e];
  float mu = wred_sum(s) * (1.0f/512.0f);
  float qq = 0.f;
  #pragma unroll
  for (int e = 0; e < 8; ++e){ float d = v[e] - mu; qq += d*d; }
  float var = wred_sum(qq) * (1.0f/512.0f);
  float inv = 1.0f / sqrtf(var + LN_EPS);
  fx4 g0 = *(const fx4*)&g[l*8], g1 = *(const fx4*)&g[l*8 + 4];
  fx4 b0 = *(const fx4*)&b[l*8], b1 = *(const fx4*)&b[l*8 + 4];
  us16x8 o;
  #pragma unroll
  for (int e = 0; e < 4; ++e){
    o[e]     = f2bf((v[e]   - mu) * inv * g0[e] + b0[e]);
    o[e + 4] = f2bf((v[e+4] - mu) * inv * g1[e] + b1[e]);
  }
  *(us16x8*)(out + base) = o;
}

// ---------------- final weighted sum + polar ----------------
__global__ __launch_bounds__(512) void final_kernel(
    const us16* __restrict__ hfin, const float* __restrict__ wsm,
    const float* __restrict__ ph, float* __restrict__ out)
{
  int bc = blockIdx.x, d = threadIdx.x;
  __shared__ float wv[TDIM];
  if (d < TDIM) wv[d] = wsm[(size_t)bc*TDIM + d];
  __syncthreads();
  float fs = 0.f;
  for (int t = 0; t < TDIM; ++t)
    fs += bf2f(hfin[((size_t)bc*TDIM + t)*DDIM + d]) * wv[t];
  float p = ph[(size_t)bc*LDIM + d];
  float sn, cs; sincosf(p, &sn, &cs);
  out[((size_t)bc*LDIM + d)*2 + 0] = fs * cs;
  out[((size_t)bc*LDIM + d)*2 + 1] = fs * sn;
}

// ---------------- launch ----------------
extern "C" void kernel_launch(void* const* d_in, const int* in_sizes, int n_in,
                              void* d_out, int out_size, void* d_ws, size_t ws_size,
                              hipStream_t stream)
{
  const float* xr    = (const float*)d_in[0];
  const float* xi    = (const float*)d_in[1];
  const float* noise = (const float*)d_in[2];
  const float* Amat  = (const float*)d_in[3];
  const float* wA    = (const float*)d_in[4];
  const float* wP    = (const float*)d_in[5];
  const float* Wq    = (const float*)d_in[6];
  const float* bq    = (const float*)d_in[7];
  const float* Wk    = (const float*)d_in[8];
  const float* bk    = (const float*)d_in[9];
  const float* Wv    = (const float*)d_in[10];
  const float* bv    = (const float*)d_in[11];
  const float* Wo    = (const float*)d_in[12];
  const float* bo    = (const float*)d_in[13];
  const float* Wc1   = (const float*)d_in[14];
  const float* bc1   = (const float*)d_in[15];
  const float* Wc2   = (const float*)d_in[16];
  const float* bc2   = (const float*)d_in[17];
  const float* g1    = (const float*)d_in[18];
  const float* b1    = (const float*)d_in[19];
  const float* g2    = (const float*)d_in[20];
  const float* b2    = (const float*)d_in[21];
  const float* gf    = (const float*)d_in[22];
  const float* bfin  = (const float*)d_in[23];
  float* out = (float*)d_out;

  char* p = (char*)d_ws;
  auto take = [&](size_t bytes) -> char* {
    char* r = p; p += (bytes + 255) & ~(size_t)255; return r;
  };
  float*  mag  = (float*)take((size_t)BC*LDIM*4);
  float*  ph   = (float*)take((size_t)BC*LDIM*4);
  double* gm   = (double*)take(LDIM*8);
  int*    idx  = (int*)take(TDIM*4);
  float*  km   = (float*)take((size_t)BC*TDIM*4);
  float*  kp   = (float*)take((size_t)BC*TDIM*4);
  float*  kr   = (float*)take((size_t)BC*TDIM*4);
  float*  ki   = (float*)take((size_t)BC*TDIM*4);
  float*  wsm  = (float*)take((size_t)BC*TDIM*4);
  float*  mask = (float*)take(TDIM*TDIM*4);
  us16*   wqkv = (us16*)take((size_t)2*1536*512*2);
  us16*   wo3  = (us16*)take((size_t)2*512*512*2);
  us16*   wc13 = (us16*)take((size_t)2*512*512*2);
  us16*   wc23 = (us16*)take((size_t)2*512*512*2);
  float*  bqkv = (float*)take((size_t)2*1536*4);
  us16*   hb   = (us16*)take((size_t)MROWS*DDIM*2);   // bf16 residual stream
  us16*   qb   = (us16*)take((size_t)MROWS*DDIM*2);
  us16*   kb2  = (us16*)take((size_t)MROWS*DDIM*2);
  us16*   vb2  = (us16*)take((size_t)MROWS*DDIM*2);
  us16*   ob   = (us16*)take((size_t)MROWS*DDIM*2);
  us16*   t0b  = vb2;   // alias — vb2 dead once attn completes
  us16*   yb   = qb;    // alias — qb dead once attn completes

  magph_kernel<<<dim3(1024), dim3(256), 0, stream>>>(xr, xi, mag, ph);
  gm_kernel<<<dim3(LDIM), dim3(64), 0, stream>>>(mag, gm);
  topk_kernel<<<dim3(2), dim3(256), 0, stream>>>(gm, idx);
  keygather_kernel<<<dim3(BC), dim3(64), 0, stream>>>(mag, ph, idx, km, kp, kr, ki, wsm);
  hipMemsetAsync(mask, 0, TDIM*TDIM*4, stream);
  distmask_kernel<<<dim3(BDIM*TDIM), dim3(64), 0, stream>>>(km, kp, Amat, wA, wP, noise, mask);
  rel_kernel<<<dim3(66560), dim3(256), 0, stream>>>(xr, xi, kr, ki, hb);

  WPtrs wp; wp.s[0]=Wq; wp.s[1]=Wk; wp.s[2]=Wv; wp.s[3]=Wo; wp.s[4]=Wc1; wp.s[5]=Wc2;
  convert_all<<<dim3(12288), dim3(256), 0, stream>>>(wp, bq, bk, bv, wqkv, wo3, wc13, wc23, bqkv);

  dim3 gqkv(MROWS/128, 1536/128);
  dim3 g512(MROWS/128, 512/128);
  for (int l = 0; l < 2; ++l){
    gemm_bt<0><<<gqkv, 256, 0, stream>>>(hb, wqkv + (size_t)l*786432, bqkv + (size_t)l*1536, qb, kb2, vb2);
    attn_mfma<<<dim3(BC, 8), dim3(256), 0, stream>>>(qb, kb2, vb2, mask, ob);
    gemm_bt<0><<<g512, 256, 0, stream>>>(ob, wo3 + (size_t)l*262144, bo + (size_t)l*DDIM, t0b, t0b, t0b);
    ln_kernel<<<dim3(MROWS/4), dim3(256), 0, stream>>>(t0b, hb, g1 + (size_t)l*DDIM, b1 + (size_t)l*DDIM, hb);
    gemm_bt<2><<<g512, 256, 0, stream>>>(hb, wc13 + (size_t)l*262144, bc1 + (size_t)l*DDIM, yb, yb, yb);
    gemm_bt<0><<<g512, 256, 0, stream>>>(yb, wc23 + (size_t)l*262144, bc2 + (size_t)l*DDIM, t0b, t0b, t0b);
    ln_kernel<<<dim3(MROWS/4), dim3(256), 0, stream>>>(t0b, hb, g2 + (size_t)l*DDIM, b2 + (size_t)l*DDIM, hb);
  }
  ln_kernel<<<dim3(MROWS/4), dim3(256), 0, stream>>>(hb, nullptr, gf, bfin, t0b);
  final_kernel<<<dim3(BC), dim3(512), 0, stream>>>(t0b, wsm, ph, out);
}

// Round 9
// 769.540 us; speedup vs baseline: 3.4274x; 1.0671x over previous
//
#include <hip/hip_runtime.h>
#include <hip/hip_bf16.h>

// ---------------- static problem config ----------------
#define BDIM 16
#define CDIM 32
#define LDIM 512
#define TDIM 65            // all_topk
#define DDIM 512
#define BC   (BDIM*CDIM)   // 512
#define MROWS (BC*TDIM)    // 33280
#define LN_EPS 1e-5f

typedef float fx4 __attribute__((ext_vector_type(4)));
typedef __bf16 bf16x8 __attribute__((ext_vector_type(8)));
typedef unsigned short us16;
typedef unsigned short us16x8 __attribute__((ext_vector_type(8)));

// ---------------- helpers ----------------
__device__ __forceinline__ us16 f2bf(float f){
  unsigned int u = __float_as_uint(f);
  u = (u + 0x7fffu + ((u >> 16) & 1u)) >> 16;
  return (us16)u;
}
__device__ __forceinline__ float bf2f(us16 s){
  return __uint_as_float(((unsigned int)s) << 16);
}
__device__ __forceinline__ float wred_max(float v){
  #pragma unroll
  for (int o = 32; o; o >>= 1) v = fmaxf(v, __shfl_xor(v, o));
  return v;
}
__device__ __forceinline__ float wred_sum(float v){
  #pragma unroll
  for (int o = 32; o; o >>= 1) v += __shfl_xor(v, o);
  return v;
}
__device__ __forceinline__ float gelu_exact(float x){
  return 0.5f * x * (1.0f + erff(x * 0.70710678118654752440f));
}
__device__ __forceinline__ void async16(void* lds, const void* g){
  __builtin_amdgcn_global_load_lds(
      (const __attribute__((address_space(1))) unsigned int*)g,
      (__attribute__((address_space(3))) unsigned int*)lds, 16, 0, 0);
}

// ---------------- K1: magnitude / phase ----------------
__global__ __launch_bounds__(256) void magph_kernel(
    const float* __restrict__ xr, const float* __restrict__ xi,
    float* __restrict__ mag, float* __restrict__ ph)
{
  int i = blockIdx.x * 256 + threadIdx.x;   // n = 262144 exact
  float r = xr[i], im = xi[i];
  mag[i] = sqrtf(r*r + im*im);
  ph[i]  = atan2f(im, r);
}

// ---------------- K2: per-frequency energy (double accum) ----------------
__global__ __launch_bounds__(64) void gm_kernel(
    const float* __restrict__ mag, double* __restrict__ gm)
{
  int l = blockIdx.x, t = threadIdx.x;
  double acc = 0.0;
  #pragma unroll
  for (int r = 0; r < 8; ++r){
    float v = mag[(size_t)(t + 64*r)*LDIM + l];
    acc += (double)v * (double)v;
  }
  #pragma unroll
  for (int o = 32; o; o >>= 1) acc += __shfl_xor(acc, o);
  if (t == 0) gm[l] = acc;
}

// ---------------- K3: parallel rank-select top-k ----------------
// rank_i = #{o : gm[o] > gm[i] or (gm[o]==gm[i] and o<i)}  == stable argsort(-gm) position.
__global__ __launch_bounds__(256) void topk_kernel(
    const double* __restrict__ gm, int* __restrict__ idxo)
{
  __shared__ float val[LDIM];
  int t = threadIdx.x;
  int i = blockIdx.x * 256 + t;
  val[t] = (float)gm[t];
  val[t + 256] = (float)gm[t + 256];
  __syncthreads();
  float vi = val[i];
  int band = (i < 170) ? 0 : (i < 340 ? 1 : 2);
  int lo = band * 170;
  int hi = (band == 2) ? LDIM : lo + 170;
  int gr = 0, br = 0;
  #pragma unroll 4
  for (int o = 0; o < LDIM; ++o){
    float vo = val[o];
    bool ahead = (vo > vi) || (vo == vi && o < i);
    gr += ahead ? 1 : 0;
    br += (ahead && o >= lo && o < hi) ? 1 : 0;
  }
  if (gr < 32) idxo[gr] = i;
  if (br < 11) idxo[32 + band*11 + br] = i;
}

// ---------------- K4: gather key freqs + softmax weights ----------------
__global__ __launch_bounds__(64) void keygather_kernel(
    const float* __restrict__ mag, const float* __restrict__ ph, const int* __restrict__ idx,
    float* __restrict__ km, float* __restrict__ kp,
    float* __restrict__ kr, float* __restrict__ ki, float* __restrict__ wsm)
{
  int bc = blockIdx.x, t = threadIdx.x;
  int i0 = idx[t];
  int i1 = idx[64];
  float m0 = mag[(size_t)bc*LDIM + i0];
  float p0 = ph [(size_t)bc*LDIM + i0];
  float m1 = mag[(size_t)bc*LDIM + i1];
  float p1 = ph [(size_t)bc*LDIM + i1];
  size_t o = (size_t)bc*TDIM;
  km[o + t] = m0; kp[o + t] = p0;
  kr[o + t] = m0 * cosf(p0); ki[o + t] = m0 * sinf(p0);
  if (t == 0){
    km[o+64] = m1; kp[o+64] = p1;
    kr[o+64] = m1*cosf(p1); ki[o+64] = m1*sinf(p1);
  }
  // softmax over 65 key magnitudes
  float mx = wred_max(fmaxf(m0, m1));
  float e0 = expf(m0 - mx), e1 = expf(m1 - mx);
  float sum = wred_sum(e0) + e1;
  wsm[o + t] = e0 / sum;
  if (t == 0) wsm[o + 64] = e1 / sum;
}

// ---------------- K5: prob-distance + gumbel mask ----------------
__global__ __launch_bounds__(64) void distmask_kernel(
    const float* __restrict__ km, const float* __restrict__ kp,
    const float* __restrict__ A, const float* __restrict__ wAs, const float* __restrict__ wPs,
    const float* __restrict__ noise, float* __restrict__ mask)
{
  int b = blockIdx.x / TDIM, i = blockIdx.x % TDIM;
  int l = threadIdx.x;
  __shared__ float kmi[CDIM], kpi[CDIM];
  if (l < CDIM){
    kmi[l] = km[(size_t)(b*CDIM + l)*TDIM + i];
    kpi[l] = kp[(size_t)(b*CDIM + l)*TDIM + i];
  }
  __syncthreads();
  float wa = wAs[0], wp = wPs[0];
  float ed0, ed1 = 0.f;
  {
    int j = l;
    float Ad = A[j*TDIM + j];
    float acc = 0.f;
    for (int c = 0; c < CDIM; ++c){
      float d = Ad * (wa*(kmi[c] - km[(size_t)(b*CDIM+c)*TDIM + j])
                    + wp*(kpi[c] - kp[(size_t)(b*CDIM+c)*TDIM + j]));
      acc += d*d;
    }
    ed0 = (j == i) ? 0.f : 1.0f/(acc + 1e-10f);
  }
  if (l == 0){
    int j = 64;
    float Ad = A[j*TDIM + j];
    float acc = 0.f;
    for (int c = 0; c < CDIM; ++c){
      float d = Ad * (wa*(kmi[c] - km[(size_t)(b*CDIM+c)*TDIM + j])
                    + wp*(kpi[c] - kp[(size_t)(b*CDIM+c)*TDIM + j]));
      acc += d*d;
    }
    ed1 = (j == i) ? 0.f : 1.0f/(acc + 1e-10f);
  }
  float mx = ed0;
  if (l == 0) mx = fmaxf(mx, ed1);
  mx = wred_max(mx);
  {
    int j = l;
    float pv = (j == i) ? 0.99f : 0.99f * (ed0 / mx);
    float logit = logf(pv / (1.0f - pv));
    size_t n = ((size_t)b*TDIM + i)*TDIM + j;
    float g0 = noise[2*n], g1 = noise[2*n + 1];
    if (logit + g0 >= g1 - logit) atomicAdd(&mask[i*TDIM + j], 0.0625f);
  }
  if (l == 0){
    int j = 64;
    float pv = (j == i) ? 0.99f : 0.99f * (ed1 / mx);
    float logit = logf(pv / (1.0f - pv));
    size_t n = ((size_t)b*TDIM + i)*TDIM + j;
    float g0 = noise[2*n], g1 = noise[2*n + 1];
    if (logit + g0 >= g1 - logit) atomicAdd(&mask[i*TDIM + j], 0.0625f);
  }
}

// ---------------- K6: relationship tensor (complex sigmoid real part) ----------------
__global__ __launch_bounds__(256) void rel_kernel(
    const float* __restrict__ xr, const float* __restrict__ xi,
    const float* __restrict__ kr, const float* __restrict__ ki,
    us16* __restrict__ hb)
{
  size_t e = (size_t)blockIdx.x * 256 + threadIdx.x;  // 17,039,360 exact
  int d = (int)(e & 511);
  size_t mt = e >> 9;
  int t  = (int)(mt % TDIM);
  int bc = (int)(mt / TDIM);
  float krv = kr[(size_t)bc*TDIM + t], kiv = ki[(size_t)bc*TDIM + t];
  float r = xr[(size_t)bc*LDIM + d], im = xi[(size_t)bc*LDIM + d];
  float a  = krv*r - kiv*im;
  float bb = krv*im + kiv*r;
  float ea = expf(-a);
  float sn, cs; sincosf(bb, &sn, &cs);
  float wr = 1.0f + ea*cs;
  float wi = -ea*sn;
  float rel = wr / (wr*wr + wi*wi);
  hb[e] = f2bf(rel);
}

// ---------------- fused weight convert + QKV concat + bias concat ----------------
struct WPtrs { const float* s[6]; };
__global__ __launch_bounds__(256) void convert_all(
    WPtrs wp, const float* __restrict__ bq, const float* __restrict__ bk,
    const float* __restrict__ bv,
    us16* __restrict__ wqkv, us16* __restrict__ wo,
    us16* __restrict__ wc1, us16* __restrict__ wc2, float* __restrict__ bqkv)
{
  size_t i = (size_t)blockIdx.x * 256 + threadIdx.x;   // 3,145,728 exact
  int m   = (int)(i >> 19);        // matrix 0..5
  int rem = (int)(i & 524287);     // [2][512][512] flat
  int l   = rem >> 18;
  us16 b = f2bf(wp.s[m][rem]);
  if (m < 3)      wqkv[(size_t)l*786432 + m*262144 + (rem & 262143)] = b;
  else if (m == 3) wo[rem]  = b;
  else if (m == 4) wc1[rem] = b;
  else             wc2[rem] = b;
  if (i < 3072){
    int l2 = (int)(i >> 11);       // 0 or 1 (1536 per layer)
    int n  = (int)(i & 1535);
    int mm = n >> 9, c = n & 511;
    const float* bs = (mm == 0) ? bq : ((mm == 1) ? bk : bv);
    bqkv[i] = bs[l2*512 + c];
  }
}

// ---------------- GEMM: C[m,n] = sum_k X[m,k]*W[n,k] + bias[n] ----------------
// 128x128 tile, BK=64, 4 waves (2x2), mfma_f32_16x16x32_bf16, 32 KB LDS.
// LDS rows of 8 16B-slots, slot XOR-swizzled by (row&7) on both sides (rule #21).
// Block-index swizzle (T1 + L2 blocking): 1D grid, xcd = bid&7 (HW round-robin);
// each XCD owns 33 m-tiles (260 padded to 264; phantoms exit); within an XCD,
// groups of 11 m-tiles iterate n fastest -> X panel (1.4 MB) + W tiles (<=1.5 MB)
// stay resident in the 4 MB per-XCD L2. Output routed by fused-N block.
// EPI: 0 = store bf16 ; 2 = gelu -> bf16.  NT = n-tiles (12 QKV / 4 others).
template<int EPI, int NT>
__global__ __launch_bounds__(256) void gemm_bt(
    const us16* __restrict__ X, const us16* __restrict__ W,
    const float* __restrict__ bias,
    us16* __restrict__ o0, us16* __restrict__ o1, us16* __restrict__ o2)
{
  const int bid = blockIdx.x;
  const int xcd = bid & 7;
  const int p   = bid >> 3;            // [0, 33*NT)
  const int mi_ = p % 11;
  const int nt  = (p / 11) % NT;
  const int mg  = p / (11*NT);
  const int m_tile = xcd*33 + mg*11 + mi_;
  if (m_tile >= 260) return;           // block-uniform exit (phantom tile)
  const int m0 = m_tile * 128, n0 = nt * 128;

  __shared__ us16 As[128*64];
  __shared__ us16 Bs[128*64];
  const int tid = threadIdx.x;
  const int w = tid >> 6, l = tid & 63;
  const int wm = w >> 1, wn = w & 1;
  const int g = l >> 4, li = l & 15;
  fx4 acc[4][4] = {};

  for (int k0 = 0; k0 < 512; k0 += 64){
    #pragma unroll
    for (int q = 0; q < 4; ++q){
      int c = q*256 + tid;          // 0..1023 ; per wave contiguous in lane
      int row = c >> 3, ps = c & 7;
      int sl = ps ^ (row & 7);      // involution
      async16(&As[c*8], X + (size_t)(m0 + row)*512 + k0 + sl*8);
      async16(&Bs[c*8], W + (size_t)(n0 + row)*512 + k0 + sl*8);
    }
    __syncthreads();
    #pragma unroll
    for (int kk = 0; kk < 2; ++kk){
      bf16x8 aF[4], bF[4];
      #pragma unroll
      for (int mi = 0; mi < 4; ++mi){
        int r = wm*64 + mi*16 + li;
        int s = (kk*4 + g) ^ (r & 7);
        aF[mi] = *reinterpret_cast<const bf16x8*>(&As[(r*8 + s)*8]);
      }
      #pragma unroll
      for (int ni = 0; ni < 4; ++ni){
        int rn = wn*64 + ni*16 + li;
        int s = (kk*4 + g) ^ (rn & 7);
        bF[ni] = *reinterpret_cast<const bf16x8*>(&Bs[(rn*8 + s)*8]);
      }
      #pragma unroll
      for (int mi = 0; mi < 4; ++mi)
        #pragma unroll
        for (int ni = 0; ni < 4; ++ni)
          acc[mi][ni] = __builtin_amdgcn_mfma_f32_16x16x32_bf16(aF[mi], bF[ni], acc[mi][ni], 0, 0, 0);
    }
    __syncthreads();
  }

  // epilogue — C/D layout: col = lane&15, row = (lane>>4)*4 + reg  [m89-verified]
  const int sel = n0 >> 9;                 // block-uniform (128 | 512)
  us16* dst = (sel == 0) ? o0 : ((sel == 1) ? o1 : o2);
  #pragma unroll
  for (int mi = 0; mi < 4; ++mi){
    #pragma unroll
    for (int ni = 0; ni < 4; ++ni){
      int coln = wn*64 + ni*16 + li;
      float bv = bias[n0 + coln];
      int col = (n0 & 511) + coln;
      #pragma unroll
      for (int r = 0; r < 4; ++r){
        int row = m0 + wm*64 + mi*16 + g*4 + r;
        float v = acc[mi][ni][r] + bv;
        if (EPI == 2) v = gelu_exact(v);
        dst[(size_t)row*512 + col] = f2bf(v);
      }
    }
  }
}

// ---------------- attention: MFMA flash-style, one (bn,h) per 256-thr block ----
// Qs/Ks: [80][64] bf16, 8 slots/row XOR-swizzled by (row&7). Vt: V^T [64][96],
// slots<8 swizzled, slots>=8 identity; k in [65,96) zeroed (NaN x 0 guard).
// Pb: P bf16 [80][96], slots<8 swizzled, slots 8..9 written (incl. zeros for
// j in [65,80)), slots 10..11 zeroed.
__global__ __launch_bounds__(256) void attn_mfma(
    const us16* __restrict__ qb, const us16* __restrict__ kb, const us16* __restrict__ vb,
    const float* __restrict__ mask, us16* __restrict__ ob)
{
  __shared__ __align__(16) us16 Qs[80*64];
  __shared__ __align__(16) us16 Ks[80*64];
  __shared__ __align__(16) us16 Vt[64*96];
  __shared__ __align__(16) us16 Pb[80*96];
  const int bn = blockIdx.x, h = blockIdx.y;
  const int tid = threadIdx.x;
  const int w = tid >> 6, l = tid & 63;
  const int g = l >> 4, li = l & 15;
  const size_t gbase = ((size_t)bn*TDIM)*512 + h*64;

  // ---- phase A: zero tails, async-stage Q/K rows 0..63, reg-load V + row 64 ----
  {
    uint4 z = {0u,0u,0u,0u};
    if (tid < 160){ int r = tid >> 1, sl = 10 + (tid & 1); *(uint4*)&Pb[r*96 + sl*8] = z; }
    if (tid < 192){ int r = tid & 63, sl = 9 + (tid >> 6); *(uint4*)&Vt[r*96 + sl*8] = z; }
  }
  #pragma unroll
  for (int it = 0; it < 2; ++it){
    int u = it*256 + tid;           // 0..511  -> rows 0..63, 8 slots each
    int r = u >> 3, ps = u & 7;
    int slog = ps ^ (r & 7);
    async16(&Qs[(it*256 + w*64)*8], qb + gbase + (size_t)r*512 + slog*8);
    async16(&Ks[(it*256 + w*64)*8], kb + gbase + (size_t)r*512 + slog*8);
  }
  us16 vreg[16];
  #pragma unroll
  for (int j = 0; j < 16; ++j)
    vreg[j] = vb[gbase + (size_t)(w*16 + j)*512 + l];
  us16 v64v = 0;
  if (tid < 64) v64v = vb[gbase + (size_t)64*512 + tid];
  uint4 r64 = {};
  if (tid < 8)       r64 = *(const uint4*)(qb + gbase + (size_t)64*512 + tid*8);
  else if (tid < 16) r64 = *(const uint4*)(kb + gbase + (size_t)64*512 + (tid-8)*8);

  __syncthreads();   // Q/K rows staged, zeros done, regs ready

  // ---- phase C: Q/K row 64 + transposed V writes (2 x b128 per thread) ----
  if (tid < 8)       *(uint4*)&Qs[(64*8 + tid)*8] = r64;     // row 64: r&7==0 -> linear
  else if (tid < 16) *(uint4*)&Ks[(64*8 + (tid-8))*8] = r64;
  {
    us16x8 lo, hi;
    #pragma unroll
    for (int j = 0; j < 8; ++j){ lo[j] = vreg[j]; hi[j] = vreg[8+j]; }
    int s0 = w*2, s1 = w*2 + 1;
    *(us16x8*)&Vt[l*96 + (s0 ^ (l & 7))*8] = lo;
    *(us16x8*)&Vt[l*96 + (s1 ^ (l & 7))*8] = hi;
  }
  if (tid < 64){
    us16x8 t8 = {};
    t8[0] = v64v;
    *(us16x8*)&Vt[tid*96 + 8*8] = t8;      // slot 8 identity; k=65..71 zeroed
  }
  __syncthreads();   // Vt + row64 visible

  // ---- per-wave M-tiles: wave w -> {w} (+{4} for wave 0). No barriers below. ----
  for (int m = w; m < 5; m += 4){
    const int mbase = m*16;
    // QK^T
    fx4 acc[5] = {};
    #pragma unroll
    for (int kk = 0; kk < 2; ++kk){
      int ra = mbase + li;
      int sA = (kk*4 + g) ^ (ra & 7);
      bf16x8 aF = *(const bf16x8*)&Qs[ra*64 + sA*8];
      #pragma unroll
      for (int n = 0; n < 5; ++n){
        int rb = n*16 + li;
        int sB = (kk*4 + g) ^ (rb & 7);
        bf16x8 bF = *(const bf16x8*)&Ks[rb*64 + sB*8];
        acc[n] = __builtin_amdgcn_mfma_f32_16x16x32_bf16(aF, bF, acc[n], 0, 0, 0);
      }
    }
    // masked softmax; C layout: col = n*16+li, row = mbase + g*4 + reg
    float p[5][4];
    #pragma unroll
    for (int reg = 0; reg < 4; ++reg){
      int i = mbase + g*4 + reg;
      float sv[5], mx = -3.4e38f;
      #pragma unroll
      for (int n = 0; n < 5; ++n){
        int j = n*16 + li;
        if (j < TDIM){
          float mv = (i < TDIM) ? mask[i*TDIM + j] : 0.0f;
          sv[n] = (acc[n][reg]*mv + (1.0f - mv)*(-1e9f)) * 0.125f;
        } else sv[n] = -3.4e38f;
        mx = fmaxf(mx, sv[n]);
      }
      #pragma unroll
      for (int o = 1; o < 16; o <<= 1) mx = fmaxf(mx, __shfl_xor(mx, o));
      float sum = 0.f;
      #pragma unroll
      for (int n = 0; n < 5; ++n){
        int j = n*16 + li;
        float e = (j < TDIM) ? expf(sv[n] - mx) : 0.0f;
        p[n][reg] = e; sum += e;
      }
      #pragma unroll
      for (int o = 1; o < 16; o <<= 1) sum += __shfl_xor(sum, o);
      float inv = 1.0f / sum;
      #pragma unroll
      for (int n = 0; n < 5; ++n) p[n][reg] *= inv;
    }
    // write P -> Pb (own rows only; within-wave producer/consumer)
    #pragma unroll
    for (int n = 0; n < 5; ++n){
      int j = n*16 + li, s = j >> 3, jo = j & 7;
      #pragma unroll
      for (int reg = 0; reg < 4; ++reg){
        int r = mbase + g*4 + reg;
        int ps = (s < 8) ? (s ^ (r & 7)) : s;
        Pb[r*96 + ps*8 + jo] = f2bf(p[n][reg]);
      }
    }
    asm volatile("s_waitcnt lgkmcnt(0)" ::: "memory");
    // PV: O[i][d] = sum_j P[i][j] V[j][d]
    fx4 acc2[4] = {};
    #pragma unroll
    for (int kk = 0; kk < 3; ++kk){
      int ra = mbase + li;
      int s = kk*4 + g;
      int psA = (s < 8) ? (s ^ (ra & 7)) : s;
      bf16x8 pF = *(const bf16x8*)&Pb[ra*96 + psA*8];
      #pragma unroll
      for (int n2 = 0; n2 < 4; ++n2){
        int d = n2*16 + li;
        int psB = (s < 8) ? (s ^ (d & 7)) : s;
        bf16x8 vF = *(const bf16x8*)&Vt[d*96 + psB*8];
        acc2[n2] = __builtin_amdgcn_mfma_f32_16x16x32_bf16(pF, vF, acc2[n2], 0, 0, 0);
      }
    }
    #pragma unroll
    for (int n2 = 0; n2 < 4; ++n2){
      int d = n2*16 + li;
      #pragma unroll
      for (int reg = 0; reg < 4; ++reg){
        int i = mbase + g*4 + reg;
        if (i < TDIM) ob[gbase + (size_t)i*512 + d] = f2bf(acc2[n2][reg]);
      }
    }
  }
}

// ---------------- layernorm bf16 (+ optional bf16 residual), 4 rows/block ----------
__global__ __launch_bounds__(256) void ln_kernel(
    const us16* __restrict__ X, const us16* __restrict__ R,
    const float* __restrict__ g, const float* __restrict__ b,
    us16* __restrict__ out)
{
  int row = blockIdx.x*4 + (threadIdx.x >> 6);
  int l = threadIdx.x & 63;
  size_t base = (size_t)row*DDIM + l*8;
  us16x8 xv = *(const us16x8*)(X + base);
  float v[8];
  #pragma unroll
  for (int e = 0; e < 8; ++e) v[e] = bf2f(xv[e]);
  if (R){
    us16x8 rv = *(const us16x8*)(R + base);
    #pragma unroll
    for (int e = 0; e < 8; ++e) v[e] += bf2f(rv[e]);
  }
  float s = 0.f;
  #pragma unroll
  for (int e = 0; e < 8; ++e) s += v[e];
  float mu = wred_sum(s) * (1.0f/512.0f);
  float qq = 0.f;
  #pragma unroll
  for (int e = 0; e < 8; ++e){ float d = v[e] - mu; qq += d*d; }
  float var = wred_sum(qq) * (1.0f/512.0f);
  float inv = 1.0f / sqrtf(var + LN_EPS);
  fx4 g0 = *(const fx4*)&g[l*8], g1 = *(const fx4*)&g[l*8 + 4];
  fx4 b0 = *(const fx4*)&b[l*8], b1 = *(const fx4*)&b[l*8 + 4];
  us16x8 o;
  #pragma unroll
  for (int e = 0; e < 4; ++e){
    o[e]     = f2bf((v[e]   - mu) * inv * g0[e] + b0[e]);
    o[e + 4] = f2bf((v[e+4] - mu) * inv * g1[e] + b1[e]);
  }
  *(us16x8*)(out + base) = o;
}

// ---------------- final weighted sum + polar ----------------
__global__ __launch_bounds__(512) void final_kernel(
    const us16* __restrict__ hfin, const float* __restrict__ wsm,
    const float* __restrict__ ph, float* __restrict__ out)
{
  int bc = blockIdx.x, d = threadIdx.x;
  __shared__ float wv[TDIM];
  if (d < TDIM) wv[d] = wsm[(size_t)bc*TDIM + d];
  __syncthreads();
  float fs = 0.f;
  for (int t = 0; t < TDIM; ++t)
    fs += bf2f(hfin[((size_t)bc*TDIM + t)*DDIM + d]) * wv[t];
  float p = ph[(size_t)bc*LDIM + d];
  float sn, cs; sincosf(p, &sn, &cs);
  out[((size_t)bc*LDIM + d)*2 + 0] = fs * cs;
  out[((size_t)bc*LDIM + d)*2 + 1] = fs * sn;
}

// ---------------- launch ----------------
extern "C" void kernel_launch(void* const* d_in, const int* in_sizes, int n_in,
                              void* d_out, int out_size, void* d_ws, size_t ws_size,
                              hipStream_t stream)
{
  const float* xr    = (const float*)d_in[0];
  const float* xi    = (const float*)d_in[1];
  const float* noise = (const float*)d_in[2];
  const float* Amat  = (const float*)d_in[3];
  const float* wA    = (const float*)d_in[4];
  const float* wP    = (const float*)d_in[5];
  const float* Wq    = (const float*)d_in[6];
  const float* bq    = (const float*)d_in[7];
  const float* Wk    = (const float*)d_in[8];
  const float* bk    = (const float*)d_in[9];
  const float* Wv    = (const float*)d_in[10];
  const float* bv    = (const float*)d_in[11];
  const float* Wo    = (const float*)d_in[12];
  const float* bo    = (const float*)d_in[13];
  const float* Wc1   = (const float*)d_in[14];
  const float* bc1   = (const float*)d_in[15];
  const float* Wc2   = (const float*)d_in[16];
  const float* bc2   = (const float*)d_in[17];
  const float* g1    = (const float*)d_in[18];
  const float* b1    = (const float*)d_in[19];
  const float* g2    = (const float*)d_in[20];
  const float* b2    = (const float*)d_in[21];
  const float* gf    = (const float*)d_in[22];
  const float* bfin  = (const float*)d_in[23];
  float* out = (float*)d_out;

  char* p = (char*)d_ws;
  auto take = [&](size_t bytes) -> char* {
    char* r = p; p += (bytes + 255) & ~(size_t)255; return r;
  };
  float*  mag  = (float*)take((size_t)BC*LDIM*4);
  float*  ph   = (float*)take((size_t)BC*LDIM*4);
  double* gm   = (double*)take(LDIM*8);
  int*    idx  = (int*)take(TDIM*4);
  float*  km   = (float*)take((size_t)BC*TDIM*4);
  float*  kp   = (float*)take((size_t)BC*TDIM*4);
  float*  kr   = (float*)take((size_t)BC*TDIM*4);
  float*  ki   = (float*)take((size_t)BC*TDIM*4);
  float*  wsm  = (float*)take((size_t)BC*TDIM*4);
  float*  mask = (float*)take(TDIM*TDIM*4);
  us16*   wqkv = (us16*)take((size_t)2*1536*512*2);
  us16*   wo3  = (us16*)take((size_t)2*512*512*2);
  us16*   wc13 = (us16*)take((size_t)2*512*512*2);
  us16*   wc23 = (us16*)take((size_t)2*512*512*2);
  float*  bqkv = (float*)take((size_t)2*1536*4);
  us16*   hb   = (us16*)take((size_t)MROWS*DDIM*2);   // bf16 residual stream
  us16*   qb   = (us16*)take((size_t)MROWS*DDIM*2);
  us16*   kb2  = (us16*)take((size_t)MROWS*DDIM*2);
  us16*   vb2  = (us16*)take((size_t)MROWS*DDIM*2);
  us16*   ob   = (us16*)take((size_t)MROWS*DDIM*2);
  us16*   t0b  = vb2;   // alias — vb2 dead once attn completes
  us16*   yb   = qb;    // alias — qb dead once attn completes

  magph_kernel<<<dim3(1024), dim3(256), 0, stream>>>(xr, xi, mag, ph);
  gm_kernel<<<dim3(LDIM), dim3(64), 0, stream>>>(mag, gm);
  topk_kernel<<<dim3(2), dim3(256), 0, stream>>>(gm, idx);
  keygather_kernel<<<dim3(BC), dim3(64), 0, stream>>>(mag, ph, idx, km, kp, kr, ki, wsm);
  hipMemsetAsync(mask, 0, TDIM*TDIM*4, stream);
  distmask_kernel<<<dim3(BDIM*TDIM), dim3(64), 0, stream>>>(km, kp, Amat, wA, wP, noise, mask);
  rel_kernel<<<dim3(66560), dim3(256), 0, stream>>>(xr, xi, kr, ki, hb);

  WPtrs wp; wp.s[0]=Wq; wp.s[1]=Wk; wp.s[2]=Wv; wp.s[3]=Wo; wp.s[4]=Wc1; wp.s[5]=Wc2;
  convert_all<<<dim3(12288), dim3(256), 0, stream>>>(wp, bq, bk, bv, wqkv, wo3, wc13, wc23, bqkv);

  const int gqkv = 8*33*12;   // 3168 blocks (4 phantoms exit early)
  const int g512 = 8*33*4;    // 1056 blocks
  for (int l = 0; l < 2; ++l){
    gemm_bt<0,12><<<dim3(gqkv), 256, 0, stream>>>(hb, wqkv + (size_t)l*786432, bqkv + (size_t)l*1536, qb, kb2, vb2);
    attn_mfma<<<dim3(BC, 8), dim3(256), 0, stream>>>(qb, kb2, vb2, mask, ob);
    gemm_bt<0,4><<<dim3(g512), 256, 0, stream>>>(ob, wo3 + (size_t)l*262144, bo + (size_t)l*DDIM, t0b, t0b, t0b);
    ln_kernel<<<dim3(MROWS/4), dim3(256), 0, stream>>>(t0b, hb, g1 + (size_t)l*DDIM, b1 + (size_t)l*DDIM, hb);
    gemm_bt<2,4><<<dim3(g512), 256, 0, stream>>>(hb, wc13 + (size_t)l*262144, bc1 + (size_t)l*DDIM, yb, yb, yb);
    gemm_bt<0,4><<<dim3(g512), 256, 0, stream>>>(yb, wc23 + (size_t)l*262144, bc2 + (size_t)l*DDIM, t0b, t0b, t0b);
    ln_kernel<<<dim3(MROWS/4), dim3(256), 0, stream>>>(t0b, hb, g2 + (size_t)l*DDIM, b2 + (size_t)l*DDIM, hb);
  }
  ln_kernel<<<dim3(MROWS/4), dim3(256), 0, stream>>>(hb, nullptr, gf, bfin, t0b);
  final_kernel<<<dim3(BC), dim3(512), 0, stream>>>(t0b, wsm, ph, out);
}